// Round 16
// baseline (723.228 us; speedup 1.0000x reference)
//
#include <hip/hip_runtime.h>

#define N_ATOMS 100000
#define E_ATOMS 200000
#define N_AMINO 10240
#define E_AMINO 20480
#define NGRAPH 512
#define DIN0 40
#define D_E 11
#define HD 20
#define D_AA 8
#define HA 128
#define KS 3
#define TL 7
#define F1 256
#define F2 128
#define F3 64
#define TILE 32
#define MC 260   // M columns: 220 edge-weight + 20 edge-bias + 20 root

typedef unsigned short u16;
typedef unsigned int u32;
typedef __attribute__((ext_vector_type(8))) short short8;
typedef __attribute__((ext_vector_type(4))) float f32x4;

__device__ __forceinline__ float b2f(u16 u) {
    union { u32 i; float f; } v; v.i = ((u32)u) << 16; return v.f;
}
__device__ __forceinline__ u16 f2b(float f) {
    union { float f; u32 i; } v; v.f = f;
    u32 x = v.i;
    return (u16)((x + (((x >> 16) & 1u) + 0x7fffu)) >> 16);
}

// ---------------------------------------------------------------------------
// prep0: M matrices (260 cols: W|b|root) + aa features + zero CSR counts.
__global__ __launch_bounds__(256) void k_prep0(
    const float* __restrict__ w1, const float* __restrict__ b1, const float* __restrict__ r1,
    const float* __restrict__ w2, const float* __restrict__ b2, const float* __restrict__ r2,
    const float* __restrict__ w3, const float* __restrict__ b3, const float* __restrict__ r3,
    float* __restrict__ M1, float* __restrict__ M2, float* __restrict__ M3,
    const float* __restrict__ af, float* __restrict__ aa,
    int* __restrict__ cs, int* __restrict__ cd,
    int* __restrict__ ca, int* __restrict__ cl) {
    int t = blockIdx.x * 256 + threadIdx.x;
    if (t < DIN0 * MC) {
        int i = t / MC, c = t % MC;
        M1[t] = (c < 220) ? w1[(c / 20) * 800 + i * 20 + (c % 20)]
              : (c < 240) ? b1[i * 20 + (c - 220)] : r1[i * 20 + (c - 240)];
    } else if (t < DIN0 * MC + HD * MC) {
        int tt = t - DIN0 * MC, i = tt / MC, c = tt % MC;
        M2[tt] = (c < 220) ? w2[(c / 20) * 400 + i * 20 + (c % 20)]
               : (c < 240) ? b2[i * 20 + (c - 220)] : r2[i * 20 + (c - 240)];
    } else if (t < DIN0 * MC + 2 * HD * MC) {
        int tt = t - DIN0 * MC - HD * MC, i = tt / MC, c = tt % MC;
        M3[tt] = (c < 220) ? w3[(c / 20) * 400 + i * 20 + (c % 20)]
               : (c < 240) ? b3[i * 20 + (c - 220)] : r3[i * 20 + (c - 240)];
    } else if (t < DIN0 * MC + 2 * HD * MC + N_AMINO * D_AA) {
        int idx = t - DIN0 * MC - 2 * HD * MC, m = idx / D_AA, j = idx % D_AA;
        aa[m * 28 + HD + j] = af[idx];
    } else {
        int z = t - DIN0 * MC - 2 * HD * MC - N_AMINO * D_AA;
        if (z < N_ATOMS) cs[z] = 0;
        else if (z < 2 * N_ATOMS) cd[z - N_ATOMS] = 0;
        else if (z < 2 * N_ATOMS + N_AMINO) ca[z - 2 * N_ATOMS] = 0;
        else if (z < 2 * N_ATOMS + 2 * N_AMINO) cl[z - 2 * N_ATOMS - N_AMINO] = 0;
    }
}
#define PREP0_N (DIN0 * MC + 2 * HD * MC + N_AMINO * D_AA + 2 * N_ATOMS + 2 * N_AMINO)

// Pack arma_w into MFMA B-fragment order, bf16.
__global__ __launch_bounds__(256) void k_cvtwp(const float* __restrict__ aw,
                                               u16* __restrict__ Wp) {
    int g = blockIdx.x * 256 + threadIdx.x;
    if (g >= (TL - 1) * KS * 16384) return;
    int mat = g >> 14, r = g & 16383;
    int kb = r >> 12, rem = r & 4095;
    int c = rem >> 5, qj = rem & 31;
    Wp[g] = f2b(aw[(size_t)mat * 16384 + (size_t)(kb * 32 + qj) * HA + c]);
}

// ---------------------------------------------------------------------------
#define NBS 98
#define NBA 10

__global__ __launch_bounds__(256) void k_csr_count(
    const int* __restrict__ esrc, const int* __restrict__ edst,
    const int* __restrict__ adst, const int* __restrict__ lbl,
    int* __restrict__ cs, int* __restrict__ cd,
    int* __restrict__ ca, int* __restrict__ cl) {
    int t = blockIdx.x * 256 + threadIdx.x;
    if (t < E_ATOMS) atomicAdd(cs + esrc[t], 1);
    else if (t < 2 * E_ATOMS) atomicAdd(cd + edst[t - E_ATOMS], 1);
    else if (t < 2 * E_ATOMS + E_AMINO) atomicAdd(ca + adst[t - 2 * E_ATOMS], 1);
    else if (t < 2 * E_ATOMS + E_AMINO + N_ATOMS) atomicAdd(cl + lbl[t - 2 * E_ATOMS - E_AMINO], 1);
}
__device__ __forceinline__ void seg_decode(int bx, int* blk, int* n, int* which) {
    if (bx < NBS)            { *which = 0; *blk = bx;             *n = N_ATOMS; }
    else if (bx < 2 * NBS)   { *which = 1; *blk = bx - NBS;       *n = N_ATOMS; }
    else if (bx < 2 * NBS + NBA) { *which = 2; *blk = bx - 2 * NBS; *n = N_AMINO; }
    else                     { *which = 3; *blk = bx - 2 * NBS - NBA; *n = N_AMINO; }
}
__global__ __launch_bounds__(256) void k_scan1(
    const int* __restrict__ cs, int* __restrict__ soff,
    const int* __restrict__ cd, int* __restrict__ doff,
    const int* __restrict__ ca, int* __restrict__ aoff,
    const int* __restrict__ cl, int* __restrict__ loff,
    int* __restrict__ bsum) {
    int blk, n, which;
    seg_decode(blockIdx.x, &blk, &n, &which);
    const int* c = which == 0 ? cs : which == 1 ? cd : which == 2 ? ca : cl;
    int* o = which == 0 ? soff : which == 1 ? doff : which == 2 ? aoff : loff;
    int tx = threadIdx.x, lane = tx & 63, w = tx >> 6;
    int i0 = blk * 1024 + tx * 4;
    int v[4];
#pragma unroll
    for (int q = 0; q < 4; ++q) v[q] = (i0 + q < n) ? c[i0 + q] : 0;
    int s = v[0] + v[1] + v[2] + v[3];
    int inc = s;
#pragma unroll
    for (int d = 1; d < 64; d <<= 1) {
        int u = __shfl_up(inc, d, 64);
        if (lane >= d) inc += u;
    }
    __shared__ int wsum[4];
    if (lane == 63) wsum[w] = inc;
    __syncthreads();
    int wo = 0;
    for (int i = 0; i < w; ++i) wo += wsum[i];
    int run = wo + inc - s;
#pragma unroll
    for (int q = 0; q < 4; ++q) {
        if (i0 + q < n) o[i0 + q] = run;
        run += v[q];
    }
    if (tx == 255) bsum[blockIdx.x] = wo + inc;
}
__global__ __launch_bounds__(128) void k_scan2(
    int* __restrict__ bsum, int* __restrict__ soff, int* __restrict__ doff,
    int* __restrict__ aoff, int* __restrict__ loff) {
    int bx = blockIdx.x;
    int nb   = (bx < 2) ? NBS : NBA;
    int base = (bx == 0) ? 0 : (bx == 1) ? NBS : (bx == 2) ? 2 * NBS : 2 * NBS + NBA;
    int* b = bsum + base;
    int tx = threadIdx.x, lane = tx & 63;
    int v = (tx < nb) ? b[tx] : 0;
    int inc = v;
#pragma unroll
    for (int d = 1; d < 64; d <<= 1) {
        int u = __shfl_up(inc, d, 64);
        if (lane >= d) inc += u;
    }
    __shared__ int w0;
    if (tx == 63) w0 = inc;
    __syncthreads();
    int excl = inc - v + ((tx >= 64) ? w0 : 0);
    if (tx < nb) b[tx] = excl;
    if (tx == nb - 1) {
        int tot = excl + v;
        if (bx == 0) soff[N_ATOMS] = tot;
        else if (bx == 1) doff[N_ATOMS] = tot;
        else if (bx == 2) aoff[N_AMINO] = tot;
        else loff[N_AMINO] = tot;
    }
}
__global__ __launch_bounds__(256) void k_scan3(
    int* __restrict__ soff, int* __restrict__ doff,
    int* __restrict__ aoff, int* __restrict__ loff,
    const int* __restrict__ bsum,
    int* __restrict__ us, int* __restrict__ ud,
    int* __restrict__ ua, int* __restrict__ ul) {
    int blk, n, which;
    seg_decode(blockIdx.x, &blk, &n, &which);
    int* o = which == 0 ? soff : which == 1 ? doff : which == 2 ? aoff : loff;
    int* cu = which == 0 ? us : which == 1 ? ud : which == 2 ? ua : ul;
    int add = bsum[blockIdx.x];
    int i0 = blk * 1024 + threadIdx.x * 4;
#pragma unroll
    for (int q = 0; q < 4; ++q)
        if (i0 + q < n) { int val = o[i0 + q] + add; o[i0 + q] = val; cu[i0 + q] = val; }
}
// fill: src slots -> srcP/eaP(bf16), dst->slot, amino eids + nrm, label->node
__global__ __launch_bounds__(256) void k_csr_fill(
    const int* __restrict__ esrc, const int* __restrict__ edst,
    const float* __restrict__ ea,
    int* __restrict__ us, int* __restrict__ srcP, u16* __restrict__ eaP,
    int* __restrict__ ud, int* __restrict__ dslot,
    const int* __restrict__ aei, int* __restrict__ ua, int* __restrict__ aeid,
    const int* __restrict__ aoff, float* __restrict__ nrm,
    const int* __restrict__ lbl, int* __restrict__ ul, int* __restrict__ lnid) {
    int t = blockIdx.x * 256 + threadIdx.x;
    if (t < E_ATOMS) {
        int jj = atomicAdd(us + esrc[t], 1);
        srcP[jj] = esrc[t];
        const float* e0 = ea + (size_t)t * D_E;
        u16* e1 = eaP + (size_t)jj * D_E;
#pragma unroll
        for (int k = 0; k < D_E; ++k) e1[k] = f2b(e0[k]);
        int p = atomicAdd(ud + edst[t], 1);
        dslot[p] = jj;
    } else if (t < E_ATOMS + E_AMINO) {
        int e = t - E_ATOMS;
        int p = atomicAdd(ua + aei[E_AMINO + e], 1);
        aeid[p] = e;
    } else if (t < E_ATOMS + 2 * E_AMINO) {
        int e = t - E_ATOMS - E_AMINO;
        int s = aei[e], d = aei[E_AMINO + e];
        int ds = aoff[s + 1] - aoff[s], dd = aoff[d + 1] - aoff[d];
        float a = ds > 0 ? rsqrtf((float)ds) : 0.f;
        float b = dd > 0 ? rsqrtf((float)dd) : 0.f;
        nrm[e] = a * b;
    } else if (t < E_ATOMS + 2 * E_AMINO + N_ATOMS) {
        int n = t - E_ATOMS - 2 * E_AMINO;
        int p = atomicAdd(ul + lbl[n], 1);
        lnid[p] = n;
    }
}

// ---------------------------------------------------------------------------
// NNConv edge: 32-node tiles. Phase 1 computes y (edge cols, LDS) AND the
// root-term cols (240..259) straight into hout (bf16, pre-bias, pre-relu).
// Phase 2 walks src-CSR, writes per-edge bf16 msg. No atomics.
template <int DIN, bool RAW>
__global__ __launch_bounds__(256) void nnconv_edge5(
    const void* __restrict__ xin, const u16* __restrict__ eaP,
    const int* __restrict__ srcP, const int* __restrict__ soff,
    const float* __restrict__ Mg, u16* __restrict__ msg,
    u16* __restrict__ hout) {
    __shared__ float y[TILE * 240];
    int tx = threadIdx.x;
    int n0 = blockIdx.x * TILE;
    // chunk 0: cols 0..255
    {
        int c = tx;
        float m[DIN];
#pragma unroll
        for (int i = 0; i < DIN; ++i) m[i] = Mg[i * MC + c];
        for (int nl = 0; nl < TILE; ++nl) {
            const float* xf = (const float*)xin + (size_t)(n0 + nl) * DIN;
            const u16*   xb = (const u16*)xin + (size_t)(n0 + nl) * DIN;
            float acc = 0.f;
#pragma unroll
            for (int i = 0; i < DIN; ++i)
                acc += (RAW ? xf[i] : b2f(xb[i])) * m[i];
            if (c < 240) y[nl * 240 + c] = acc;
            else hout[(size_t)(n0 + nl) * HD + (c - 240)] = f2b(acc);
        }
    }
    // chunk 1: cols 256..259 (root cols 16..19)
    if (tx < 4) {
        int c = 256 + tx;
        float m[DIN];
#pragma unroll
        for (int i = 0; i < DIN; ++i) m[i] = Mg[i * MC + c];
        for (int nl = 0; nl < TILE; ++nl) {
            const float* xf = (const float*)xin + (size_t)(n0 + nl) * DIN;
            const u16*   xb = (const u16*)xin + (size_t)(n0 + nl) * DIN;
            float acc = 0.f;
#pragma unroll
            for (int i = 0; i < DIN; ++i)
                acc += (RAW ? xf[i] : b2f(xb[i])) * m[i];
            hout[(size_t)(n0 + nl) * HD + (c - 240)] = f2b(acc);
        }
    }
    __syncthreads();
    int j0 = soff[n0], j1 = soff[n0 + TILE];
    if (tx < 240) {
        int o = tx % 20, grp = tx / 20;
        for (int jj = j0 + grp; jj < j1; jj += 12) {
            int sl = srcP[jj] - n0;
            const u16* er = eaP + (size_t)jj * D_E;
            float mv = y[sl * 240 + 220 + o];
#pragma unroll
            for (int k = 0; k < D_E; ++k) mv += b2f(er[k]) * y[sl * 240 + k * HD + o];
            msg[(size_t)jj * 20 + o] = f2b(mv);
        }
    }
}

// NNConv reduce (in place): h[t] = relu(rootterm(h[t]) + bias[o] + sum msgs)
__global__ __launch_bounds__(256) void nnconv_reduce2(
    const float* __restrict__ bias, const int* __restrict__ doff,
    const int* __restrict__ dslot, const u16* __restrict__ msg,
    u16* __restrict__ h) {
    int t = blockIdx.x * 256 + threadIdx.x;
    if (t >= N_ATOMS * HD) return;
    int n = t / HD, o = t % HD;
    float acc = b2f(h[t]) + bias[o];
    int j1 = doff[n + 1];
    for (int j = doff[n]; j < j1; ++j)
        acc += b2f(msg[(size_t)dslot[j] * 20 + o]);
    h[t] = f2b(fmaxf(acc, 0.f));
}

// aa gather: label-CSR segmented sum of h3
__global__ __launch_bounds__(256) void aa_gather(
    const u16* __restrict__ h3, const int* __restrict__ loff,
    const int* __restrict__ lnid, float* __restrict__ aa) {
    int t = blockIdx.x * 256 + threadIdx.x;
    if (t >= N_AMINO * HD) return;
    int m = t / HD, o = t % HD;
    float s = 0.f;
    int j1 = loff[m + 1];
    for (int j = loff[m]; j < j1; ++j)
        s += b2f(h3[(size_t)lnid[j] * HD + o]);
    aa[m * 28 + o] = s;
}

// ---------------------------------------------------------------------------
// ARMA gemm28: H(bf16) = aa @ W[k], W + aa-tile in LDS.
__global__ __launch_bounds__(256) void arma_gemm28(
    const float* __restrict__ A, const float* __restrict__ W, size_t wstride,
    u16* __restrict__ H, size_t hstride) {
    __shared__ float Wl[28 * 128];
    __shared__ float Aas[16][28];
    int tx = threadIdx.x;
    const float* Wk = W + blockIdx.y * wstride;
    int n0 = blockIdx.x * 16;
    for (int i = tx; i < 28 * 128; i += 256) Wl[i] = Wk[i];
    for (int i = tx; i < 16 * 28; i += 256)
        Aas[i / 28][i % 28] = A[(size_t)(n0 + i / 28) * 28 + i % 28];
    __syncthreads();
    int nl = tx >> 4, c0 = (tx & 15) * 8;
    u16* Hk = H + blockIdx.y * hstride;
    float acc[8];
#pragma unroll
    for (int j = 0; j < 8; ++j) acc[j] = 0.f;
    for (int f = 0; f < 28; ++f) {
        float av = Aas[nl][f];
        const float* wr = &Wl[f * 128 + c0];
        float4 w0 = *(const float4*)wr, w1 = *(const float4*)(wr + 4);
        acc[0] += av * w0.x; acc[1] += av * w0.y; acc[2] += av * w0.z; acc[3] += av * w0.w;
        acc[4] += av * w1.x; acc[5] += av * w1.y; acc[6] += av * w1.z; acc[7] += av * w1.w;
    }
    uint4 pk;
    pk.x = (u32)f2b(acc[0]) | ((u32)f2b(acc[1]) << 16);
    pk.y = (u32)f2b(acc[2]) | ((u32)f2b(acc[3]) << 16);
    pk.z = (u32)f2b(acc[4]) | ((u32)f2b(acc[5]) << 16);
    pk.w = (u32)f2b(acc[6]) | ((u32)f2b(acc[7]) << 16);
    *(uint4*)(Hk + (size_t)(n0 + nl) * HA + c0) = pk;
}

// ARMA gemm via MFMA bf16: H(bf16) = O_bf16 @ Wp_bf16.
__global__ __launch_bounds__(256) void arma_gemm_mf(
    const u16* __restrict__ Obh, size_t astride,
    const u16* __restrict__ Wp,
    u16* __restrict__ H, size_t hstride) {
    int wave = threadIdx.x >> 6, lane = threadIdx.x & 63;
    int k = blockIdx.y;
    const u16* A = Obh + (size_t)k * astride;
    const u16* W = Wp + (size_t)k * 16384;
    u16* Hk = H + (size_t)k * hstride;
    int n0 = (blockIdx.x * 4 + wave) * 16;
    int m = lane & 15, q = lane >> 4;
    short8 aF[4];
#pragma unroll
    for (int kb = 0; kb < 4; ++kb)
        aF[kb] = *(const short8*)(A + (size_t)(n0 + m) * HA + kb * 32 + q * 8);
#pragma unroll
    for (int ct = 0; ct < 8; ++ct) {
        int c0 = ct * 16;
        f32x4 acc = {0.f, 0.f, 0.f, 0.f};
#pragma unroll
        for (int kb = 0; kb < 4; ++kb) {
            short8 bF = *(const short8*)(W + (size_t)((kb * 128 + c0 + m) * 32 + q * 8));
            acc = __builtin_amdgcn_mfma_f32_16x16x32_bf16(aF[kb], bF, acc, 0, 0, 0);
        }
#pragma unroll
        for (int r = 0; r < 4; ++r)
            Hk[(size_t)(n0 + q * 4 + r) * HA + c0 + m] = f2b(acc[r]);
    }
}

// ARMA out: gather (bf16 H, uint4 loads) + root-gemm (LDS) + relu; O bf16.
__global__ __launch_bounds__(256) void arma_out(
    const u16* __restrict__ H, size_t hstride,
    const float* __restrict__ aa,
    const float* __restrict__ rw, size_t rstride,
    const float* __restrict__ bw, size_t bstride,
    const int* __restrict__ aei, const int* __restrict__ aoff,
    const int* __restrict__ aeid, const float* __restrict__ nrm,
    u16* __restrict__ O, size_t ostride) {
    __shared__ float Rw[28 * 128];
    __shared__ float Bw[128];
    __shared__ float Aas[16][28];
    int tx = threadIdx.x;
    const float* rwk = rw + blockIdx.y * rstride;
    const float* bwk = bw + blockIdx.y * bstride;
    int n0 = blockIdx.x * 16;
    for (int i = tx; i < 28 * 128; i += 256) Rw[i] = rwk[i];
    if (tx < 128) Bw[tx] = bwk[tx];
    for (int i = tx; i < 16 * 28; i += 256)
        Aas[i / 28][i % 28] = aa[(size_t)(n0 + i / 28) * 28 + i % 28];
    __syncthreads();
    int nl = tx >> 4, c0 = (tx & 15) * 8;
    int n = n0 + nl;
    const u16* Hk = H + blockIdx.y * hstride;
    u16* Ok = O + blockIdx.y * ostride;
    float acc[8];
#pragma unroll
    for (int j = 0; j < 8; ++j) acc[j] = Bw[c0 + j];
    int j1 = aoff[n + 1];
    for (int jj = aoff[n]; jj < j1; ++jj) {
        int e = aeid[jj], s = aei[e];
        float nm = nrm[e];
        uint4 hv = *(const uint4*)(Hk + (size_t)s * HA + c0);
        acc[0] += nm * b2f((u16)(hv.x & 0xffff));
        acc[1] += nm * b2f((u16)(hv.x >> 16));
        acc[2] += nm * b2f((u16)(hv.y & 0xffff));
        acc[3] += nm * b2f((u16)(hv.y >> 16));
        acc[4] += nm * b2f((u16)(hv.z & 0xffff));
        acc[5] += nm * b2f((u16)(hv.z >> 16));
        acc[6] += nm * b2f((u16)(hv.w & 0xffff));
        acc[7] += nm * b2f((u16)(hv.w >> 16));
    }
    for (int f = 0; f < 28; ++f) {
        float av = Aas[nl][f];
        const float* wr = &Rw[f * 128 + c0];
        float4 w0 = *(const float4*)wr, w1 = *(const float4*)(wr + 4);
        acc[0] += av * w0.x; acc[1] += av * w0.y; acc[2] += av * w0.z; acc[3] += av * w0.w;
        acc[4] += av * w1.x; acc[5] += av * w1.y; acc[6] += av * w1.z; acc[7] += av * w1.w;
    }
#pragma unroll
    for (int j = 0; j < 8; ++j) acc[j] = fmaxf(acc[j], 0.f);
    uint4 pk;
    pk.x = (u32)f2b(acc[0]) | ((u32)f2b(acc[1]) << 16);
    pk.y = (u32)f2b(acc[2]) | ((u32)f2b(acc[3]) << 16);
    pk.z = (u32)f2b(acc[4]) | ((u32)f2b(acc[5]) << 16);
    pk.w = (u32)f2b(acc[6]) | ((u32)f2b(acc[7]) << 16);
    *(uint4*)(Ok + (size_t)n * HA + c0) = pk;
}

// ---------------------------------------------------------------------------
// head2: fused readout (sorted amino_batch segmented sum over bf16 O) + MLP.
__global__ __launch_bounds__(256) void head2(
    const u16* __restrict__ O, size_t kstride, const int* __restrict__ bat,
    const float* __restrict__ l1w, const float* __restrict__ l1b,
    const float* __restrict__ l2w, const float* __restrict__ l2b,
    const float* __restrict__ l3w, const float* __restrict__ l3b,
    const float* __restrict__ l4w, const float* __restrict__ l4b,
    float* __restrict__ outp) {
    __shared__ float sg[HA], sp1[F1], sp2[F2], sp3[F3];
    int b = blockIdx.x, tx = threadIdx.x;
    int lo = 0, hi = N_AMINO;
    while (lo < hi) { int mid = (lo + hi) >> 1; if (bat[mid] < b) lo = mid + 1; else hi = mid; }
    int s = lo;
    lo = 0; hi = N_AMINO;
    while (lo < hi) { int mid = (lo + hi) >> 1; if (bat[mid] < b + 1) lo = mid + 1; else hi = mid; }
    int e = lo;
    if (tx < HA) {
        float acc = 0.f;
        for (int n = s; n < e; ++n)
            acc += b2f(O[(size_t)n * HA + tx]) + b2f(O[kstride + (size_t)n * HA + tx])
                 + b2f(O[2 * kstride + (size_t)n * HA + tx]);
        sg[tx] = acc * (1.f / 3.f);
    }
    __syncthreads();
    {   float acc = l1b[tx];
        for (int f = 0; f < HA; ++f) acc += sg[f] * l1w[f * F1 + tx];
        sp1[tx] = fmaxf(acc, 0.f); }
    __syncthreads();
    if (tx < F2) {
        float acc = l2b[tx];
        for (int f = 0; f < F1; ++f) acc += sp1[f] * l2w[f * F2 + tx];
        sp2[tx] = fmaxf(acc, 0.f); }
    __syncthreads();
    if (tx < F3) {
        float acc = l3b[tx];
        for (int f = 0; f < F2; ++f) acc += sp2[f] * l3w[f * F3 + tx];
        sp3[tx] = fmaxf(acc, 0.f); }
    __syncthreads();
    if (tx < 64) {
        float p = sp3[tx] * l4w[tx];
        for (int off = 32; off > 0; off >>= 1) p += __shfl_down(p, off, 64);
        if (tx == 0) outp[b] = p + l4b[0];
    }
}

// ---------------------------------------------------------------------------
// Workspace (<= 34,348,288 B, proven available).
#define OFF_M1    ((size_t)0)
#define OFF_M2    ((size_t)41600)
#define OFF_M3    ((size_t)62400)
#define OFF_AOFF  ((size_t)83200)
#define OFF_AEID  ((size_t)124416)
#define OFF_NRM   ((size_t)206336)
#define OFF_AA    ((size_t)288256)
#define OFF_HA    ((size_t)2891008)
#define OFF_HB    ((size_t)6891008)
#define OFF_MSG   ((size_t)10891008)
#define OFF_SOFF  ((size_t)18891008)
#define OFF_DOFF  ((size_t)19291136)
#define OFF_DSLOT ((size_t)19691264)
#define OFF_LOFF  ((size_t)20491264)
#define OFF_LNID  ((size_t)20532480)
#define OFF_CS    ((size_t)20932480)
#define OFF_CD    ((size_t)21332480)
#define OFF_CA    ((size_t)21732480)
#define OFF_CL    ((size_t)21773440)
#define OFF_US    ((size_t)21814400)
#define OFF_UD    ((size_t)22214400)
#define OFF_UA    ((size_t)22614400)
#define OFF_UL    ((size_t)22655360)
#define OFF_BSUM  ((size_t)22696320)
#define OFF_EAP   ((size_t)22697216)      // bf16 4,400,000 -> 27,097,216
#define OFF_SRCP  ((size_t)27097216)      // 800,000 -> 27,897,216
#define OFF_WP    ((size_t)27897216)      // 589,824 -> 28,487,040
// ARMA overlay: H bf16 2,891,008..10,755,328; O bf16 18,619,648..26,483,968.
#define OFF_ARH   ((size_t)2891008)
#define OFF_ARO   ((size_t)18619648)

extern "C" void kernel_launch(void* const* d_in, const int* in_sizes, int n_in,
                              void* d_out, int out_size, void* d_ws, size_t ws_size,
                              hipStream_t stream) {
    (void)in_sizes; (void)n_in; (void)out_size; (void)ws_size;
    const float* x   = (const float*)d_in[0];
    const int*   ei  = (const int*)d_in[1];
    const float* ea  = (const float*)d_in[2];
    const int*   lbl = (const int*)d_in[3];
    const float* af  = (const float*)d_in[4];
    const int*   aei = (const int*)d_in[5];
    const int*   bat = (const int*)d_in[6];
    const float* nn1w = (const float*)d_in[7];  const float* nn1b = (const float*)d_in[8];
    const float* rt1  = (const float*)d_in[9];  const float* b1   = (const float*)d_in[10];
    const float* nn2w = (const float*)d_in[11]; const float* nn2b = (const float*)d_in[12];
    const float* rt2  = (const float*)d_in[13]; const float* b2   = (const float*)d_in[14];
    const float* nn3w = (const float*)d_in[15]; const float* nn3b = (const float*)d_in[16];
    const float* rt3  = (const float*)d_in[17]; const float* b3   = (const float*)d_in[18];
    const float* ai   = (const float*)d_in[19]; const float* aw   = (const float*)d_in[20];
    const float* arw  = (const float*)d_in[21]; const float* abi  = (const float*)d_in[22];
    const float* l1w  = (const float*)d_in[23]; const float* l1b  = (const float*)d_in[24];
    const float* l2w  = (const float*)d_in[25]; const float* l2b  = (const float*)d_in[26];
    const float* l3w  = (const float*)d_in[27]; const float* l3b  = (const float*)d_in[28];
    const float* l4w  = (const float*)d_in[29]; const float* l4b  = (const float*)d_in[30];
    float* outp = (float*)d_out;

    char* ws = (char*)d_ws;
    float* M1    = (float*)(ws + OFF_M1);
    float* M2    = (float*)(ws + OFF_M2);
    float* M3    = (float*)(ws + OFF_M3);
    int*   aoff  = (int*)(ws + OFF_AOFF);
    int*   aeid  = (int*)(ws + OFF_AEID);
    float* nrm   = (float*)(ws + OFF_NRM);
    float* aa    = (float*)(ws + OFF_AA);
    u16*   hA    = (u16*)(ws + OFF_HA);
    u16*   hB    = (u16*)(ws + OFF_HB);
    u16*   msg   = (u16*)(ws + OFF_MSG);
    int*   soff  = (int*)(ws + OFF_SOFF);
    int*   doff  = (int*)(ws + OFF_DOFF);
    int*   dslot = (int*)(ws + OFF_DSLOT);
    int*   loff  = (int*)(ws + OFF_LOFF);
    int*   lnid  = (int*)(ws + OFF_LNID);
    int*   cs    = (int*)(ws + OFF_CS);
    int*   cd    = (int*)(ws + OFF_CD);
    int*   ca    = (int*)(ws + OFF_CA);
    int*   cl    = (int*)(ws + OFF_CL);
    int*   us    = (int*)(ws + OFF_US);
    int*   ud    = (int*)(ws + OFF_UD);
    int*   ua    = (int*)(ws + OFF_UA);
    int*   ul    = (int*)(ws + OFF_UL);
    int*   bsum  = (int*)(ws + OFF_BSUM);
    u16*   eaP   = (u16*)(ws + OFF_EAP);
    int*   srcP  = (int*)(ws + OFF_SRCP);
    u16*   Wp    = (u16*)(ws + OFF_WP);
    u16*   Hb    = (u16*)(ws + OFF_ARH);
    u16*   Obh   = (u16*)(ws + OFF_ARO);

    const int* esrc = ei;
    const int* edst = ei + E_ATOMS;
    const int* adst = aei + E_AMINO;

    // prep
    k_prep0<<<(PREP0_N + 255) / 256, 256, 0, stream>>>(
        nn1w, nn1b, rt1, nn2w, nn2b, rt2, nn3w, nn3b, rt3,
        M1, M2, M3, af, aa, cs, cd, ca, cl);
    k_cvtwp<<<((TL - 1) * KS * 16384 + 255) / 256, 256, 0, stream>>>(aw, Wp);
    k_csr_count<<<(2 * E_ATOMS + E_AMINO + N_ATOMS + 255) / 256, 256, 0, stream>>>(
        esrc, edst, adst, lbl, cs, cd, ca, cl);
    k_scan1<<<2 * NBS + 2 * NBA, 256, 0, stream>>>(cs, soff, cd, doff, ca, aoff, cl, loff, bsum);
    k_scan2<<<4, 128, 0, stream>>>(bsum, soff, doff, aoff, loff);
    k_scan3<<<2 * NBS + 2 * NBA, 256, 0, stream>>>(soff, doff, aoff, loff, bsum, us, ud, ua, ul);
    k_csr_fill<<<(E_ATOMS + 2 * E_AMINO + N_ATOMS + 255) / 256, 256, 0, stream>>>(
        esrc, edst, ea, us, srcP, eaP, ud, dslot, aei, ua, aeid, aoff, nrm, lbl, ul, lnid);

    // NNConv: edge(msg + root cols) + in-place reduce
    const int GT = (N_ATOMS + TILE - 1) / TILE;   // 3125
    const int GF = (N_ATOMS * HD + 255) / 256;    // 7813
    nnconv_edge5<DIN0, true ><<<GT, 256, 0, stream>>>(x,  eaP, srcP, soff, M1, msg, hA);
    nnconv_reduce2<<<GF, 256, 0, stream>>>(b1, doff, dslot, msg, hA);
    nnconv_edge5<HD,   false><<<GT, 256, 0, stream>>>(hA, eaP, srcP, soff, M2, msg, hB);
    nnconv_reduce2<<<GF, 256, 0, stream>>>(b2, doff, dslot, msg, hB);
    nnconv_edge5<HD,   false><<<GT, 256, 0, stream>>>(hB, eaP, srcP, soff, M3, msg, hA);
    nnconv_reduce2<<<GF, 256, 0, stream>>>(b3, doff, dslot, msg, hA);
    aa_gather<<<(N_AMINO * HD + 255) / 256, 256, 0, stream>>>(hA, loff, lnid, aa);

    // ARMA: K-parallel, T layers; bf16 H everywhere
    const size_t KH = (size_t)N_AMINO * HA;
    for (int t = 0; t < TL; ++t) {
        if (t == 0)
            arma_gemm28<<<dim3(640, KS), 256, 0, stream>>>(aa, ai, 28 * HA, Hb, KH);
        else
            arma_gemm_mf<<<dim3(160, KS), 256, 0, stream>>>(
                Obh, KH, Wp + (size_t)(t - 1) * KS * 16384, Hb, KH);
        arma_out<<<dim3(640, KS), 256, 0, stream>>>(
            Hb, KH, aa, arw + (size_t)t * KS * 28 * HA, 28 * HA,
            abi + (size_t)t * KS * HA, HA, aei, aoff, aeid, nrm, Obh, KH);
    }

    head2<<<NGRAPH, 256, 0, stream>>>(Obh, KH, bat, l1w, l1b, l2w, l2b,
                                      l3w, l3b, l4w, l4b, outp);
}

// Round 17
// 648.623 us; speedup vs baseline: 1.1150x; 1.1150x over previous
//
#include <hip/hip_runtime.h>

#define N_ATOMS 100000
#define E_ATOMS 200000
#define N_AMINO 10240
#define E_AMINO 20480
#define NGRAPH 512
#define DIN0 40
#define D_E 11
#define HD 20
#define D_AA 8
#define HA 128
#define KS 3
#define TL 7
#define F1 256
#define F2 128
#define F3 64
#define TILE 32

typedef unsigned short u16;
typedef unsigned int u32;
typedef __attribute__((ext_vector_type(8))) short short8;
typedef __attribute__((ext_vector_type(4))) float f32x4;

__device__ __forceinline__ float b2f(u16 u) {
    union { u32 i; float f; } v; v.i = ((u32)u) << 16; return v.f;
}
__device__ __forceinline__ u16 f2b(float f) {
    union { float f; u32 i; } v; v.f = f;
    u32 x = v.i;
    return (u16)((x + (((x >> 16) & 1u) + 0x7fffu)) >> 16);
}

// ---------------------------------------------------------------------------
// prep0: M matrices (240 cols: W|b) + aa feature columns + zero CSR counts.
__global__ __launch_bounds__(256) void k_prep0(
    const float* __restrict__ w1, const float* __restrict__ b1,
    const float* __restrict__ w2, const float* __restrict__ b2,
    const float* __restrict__ w3, const float* __restrict__ b3,
    float* __restrict__ M1, float* __restrict__ M2, float* __restrict__ M3,
    const float* __restrict__ af, float* __restrict__ aa,
    int* __restrict__ cs, int* __restrict__ cd,
    int* __restrict__ ca, int* __restrict__ cl) {
    int t = blockIdx.x * 256 + threadIdx.x;
    if (t < 9600) {
        int i = t / 240, c = t % 240;
        M1[t] = (c < 220) ? w1[(c / 20) * 800 + i * 20 + (c % 20)] : b1[i * 20 + (c - 220)];
    } else if (t < 14400) {
        int tt = t - 9600, i = tt / 240, c = tt % 240;
        M2[tt] = (c < 220) ? w2[(c / 20) * 400 + i * 20 + (c % 20)] : b2[i * 20 + (c - 220)];
    } else if (t < 19200) {
        int tt = t - 14400, i = tt / 240, c = tt % 240;
        M3[tt] = (c < 220) ? w3[(c / 20) * 400 + i * 20 + (c % 20)] : b3[i * 20 + (c - 220)];
    } else if (t < 19200 + N_AMINO * D_AA) {
        int idx = t - 19200, m = idx / D_AA, j = idx % D_AA;
        aa[m * 28 + HD + j] = af[idx];
    } else {
        int z = t - 19200 - N_AMINO * D_AA;
        if (z < N_ATOMS) cs[z] = 0;
        else if (z < 2 * N_ATOMS) cd[z - N_ATOMS] = 0;
        else if (z < 2 * N_ATOMS + N_AMINO) ca[z - 2 * N_ATOMS] = 0;
        else if (z < 2 * N_ATOMS + 2 * N_AMINO) cl[z - 2 * N_ATOMS - N_AMINO] = 0;
    }
}
#define PREP0_N (19200 + N_AMINO * D_AA + 2 * N_ATOMS + 2 * N_AMINO)

// Pack arma_w into MFMA B-fragment order, bf16.
__global__ __launch_bounds__(256) void k_cvtwp(const float* __restrict__ aw,
                                               u16* __restrict__ Wp) {
    int g = blockIdx.x * 256 + threadIdx.x;
    if (g >= (TL - 1) * KS * 16384) return;
    int mat = g >> 14, r = g & 16383;
    int kb = r >> 12, rem = r & 4095;
    int c = rem >> 5, qj = rem & 31;
    Wp[g] = f2b(aw[(size_t)mat * 16384 + (size_t)(kb * 32 + qj) * HA + c]);
}

// ---------------------------------------------------------------------------
#define NBS 98
#define NBA 10

__global__ __launch_bounds__(256) void k_csr_count(
    const int* __restrict__ esrc, const int* __restrict__ edst,
    const int* __restrict__ adst, const int* __restrict__ lbl,
    int* __restrict__ cs, int* __restrict__ cd,
    int* __restrict__ ca, int* __restrict__ cl) {
    int t = blockIdx.x * 256 + threadIdx.x;
    if (t < E_ATOMS) atomicAdd(cs + esrc[t], 1);
    else if (t < 2 * E_ATOMS) atomicAdd(cd + edst[t - E_ATOMS], 1);
    else if (t < 2 * E_ATOMS + E_AMINO) atomicAdd(ca + adst[t - 2 * E_ATOMS], 1);
    else if (t < 2 * E_ATOMS + E_AMINO + N_ATOMS) atomicAdd(cl + lbl[t - 2 * E_ATOMS - E_AMINO], 1);
}
__device__ __forceinline__ void seg_decode(int bx, int* blk, int* n, int* which) {
    if (bx < NBS)            { *which = 0; *blk = bx;             *n = N_ATOMS; }
    else if (bx < 2 * NBS)   { *which = 1; *blk = bx - NBS;       *n = N_ATOMS; }
    else if (bx < 2 * NBS + NBA) { *which = 2; *blk = bx - 2 * NBS; *n = N_AMINO; }
    else                     { *which = 3; *blk = bx - 2 * NBS - NBA; *n = N_AMINO; }
}
__global__ __launch_bounds__(256) void k_scan1(
    const int* __restrict__ cs, int* __restrict__ soff,
    const int* __restrict__ cd, int* __restrict__ doff,
    const int* __restrict__ ca, int* __restrict__ aoff,
    const int* __restrict__ cl, int* __restrict__ loff,
    int* __restrict__ bsum) {
    int blk, n, which;
    seg_decode(blockIdx.x, &blk, &n, &which);
    const int* c = which == 0 ? cs : which == 1 ? cd : which == 2 ? ca : cl;
    int* o = which == 0 ? soff : which == 1 ? doff : which == 2 ? aoff : loff;
    int tx = threadIdx.x, lane = tx & 63, w = tx >> 6;
    int i0 = blk * 1024 + tx * 4;
    int v[4];
#pragma unroll
    for (int q = 0; q < 4; ++q) v[q] = (i0 + q < n) ? c[i0 + q] : 0;
    int s = v[0] + v[1] + v[2] + v[3];
    int inc = s;
#pragma unroll
    for (int d = 1; d < 64; d <<= 1) {
        int u = __shfl_up(inc, d, 64);
        if (lane >= d) inc += u;
    }
    __shared__ int wsum[4];
    if (lane == 63) wsum[w] = inc;
    __syncthreads();
    int wo = 0;
    for (int i = 0; i < w; ++i) wo += wsum[i];
    int run = wo + inc - s;
#pragma unroll
    for (int q = 0; q < 4; ++q) {
        if (i0 + q < n) o[i0 + q] = run;
        run += v[q];
    }
    if (tx == 255) bsum[blockIdx.x] = wo + inc;
}
__global__ __launch_bounds__(128) void k_scan2(
    int* __restrict__ bsum, int* __restrict__ soff, int* __restrict__ doff,
    int* __restrict__ aoff, int* __restrict__ loff) {
    int bx = blockIdx.x;
    int nb   = (bx < 2) ? NBS : NBA;
    int base = (bx == 0) ? 0 : (bx == 1) ? NBS : (bx == 2) ? 2 * NBS : 2 * NBS + NBA;
    int* b = bsum + base;
    int tx = threadIdx.x, lane = tx & 63;
    int v = (tx < nb) ? b[tx] : 0;
    int inc = v;
#pragma unroll
    for (int d = 1; d < 64; d <<= 1) {
        int u = __shfl_up(inc, d, 64);
        if (lane >= d) inc += u;
    }
    __shared__ int w0;
    if (tx == 63) w0 = inc;
    __syncthreads();
    int excl = inc - v + ((tx >= 64) ? w0 : 0);
    if (tx < nb) b[tx] = excl;
    if (tx == nb - 1) {
        int tot = excl + v;
        if (bx == 0) soff[N_ATOMS] = tot;
        else if (bx == 1) doff[N_ATOMS] = tot;
        else if (bx == 2) aoff[N_AMINO] = tot;
        else loff[N_AMINO] = tot;
    }
}
__global__ __launch_bounds__(256) void k_scan3(
    int* __restrict__ soff, int* __restrict__ doff,
    int* __restrict__ aoff, int* __restrict__ loff,
    const int* __restrict__ bsum,
    int* __restrict__ us, int* __restrict__ ud,
    int* __restrict__ ua, int* __restrict__ ul) {
    int blk, n, which;
    seg_decode(blockIdx.x, &blk, &n, &which);
    int* o = which == 0 ? soff : which == 1 ? doff : which == 2 ? aoff : loff;
    int* cu = which == 0 ? us : which == 1 ? ud : which == 2 ? ua : ul;
    int add = bsum[blockIdx.x];
    int i0 = blk * 1024 + threadIdx.x * 4;
#pragma unroll
    for (int q = 0; q < 4; ++q)
        if (i0 + q < n) { int val = o[i0 + q] + add; o[i0 + q] = val; cu[i0 + q] = val; }
}
// fill: src slots -> srcP/eaP(bf16), dst->slot, amino eids + nrm, label->node
__global__ __launch_bounds__(256) void k_csr_fill(
    const int* __restrict__ esrc, const int* __restrict__ edst,
    const float* __restrict__ ea,
    int* __restrict__ us, int* __restrict__ srcP, u16* __restrict__ eaP,
    int* __restrict__ ud, int* __restrict__ dslot,
    const int* __restrict__ aei, int* __restrict__ ua, int* __restrict__ aeid,
    const int* __restrict__ aoff, float* __restrict__ nrm,
    const int* __restrict__ lbl, int* __restrict__ ul, int* __restrict__ lnid) {
    int t = blockIdx.x * 256 + threadIdx.x;
    if (t < E_ATOMS) {
        int jj = atomicAdd(us + esrc[t], 1);
        srcP[jj] = esrc[t];
        const float* e0 = ea + (size_t)t * D_E;
        u16* e1 = eaP + (size_t)jj * D_E;
#pragma unroll
        for (int k = 0; k < D_E; ++k) e1[k] = f2b(e0[k]);
        int p = atomicAdd(ud + edst[t], 1);
        dslot[p] = jj;
    } else if (t < E_ATOMS + E_AMINO) {
        int e = t - E_ATOMS;
        int p = atomicAdd(ua + aei[E_AMINO + e], 1);
        aeid[p] = e;
    } else if (t < E_ATOMS + 2 * E_AMINO) {
        int e = t - E_ATOMS - E_AMINO;
        int s = aei[e], d = aei[E_AMINO + e];
        int ds = aoff[s + 1] - aoff[s], dd = aoff[d + 1] - aoff[d];
        float a = ds > 0 ? rsqrtf((float)ds) : 0.f;
        float b = dd > 0 ? rsqrtf((float)dd) : 0.f;
        nrm[e] = a * b;
    } else if (t < E_ATOMS + 2 * E_AMINO + N_ATOMS) {
        int n = t - E_ATOMS - 2 * E_AMINO;
        int p = atomicAdd(ul + lbl[n], 1);
        lnid[p] = n;
    }
}

// ---------------------------------------------------------------------------
// NNConv edge (round-14 structure): 32-node tiles, y in LDS only, bf16 msg.
template <int DIN, bool RAW>
__global__ __launch_bounds__(256) void nnconv_edge3(
    const void* __restrict__ xin, const u16* __restrict__ eaP,
    const int* __restrict__ srcP, const int* __restrict__ soff,
    const float* __restrict__ Mg, u16* __restrict__ msg) {
    __shared__ float y[TILE * 240];
    int tx = threadIdx.x;
    int n0 = blockIdx.x * TILE;
    int nT = min(TILE, N_ATOMS - n0);
    if (tx < 240) {
        float m[DIN];
#pragma unroll
        for (int i = 0; i < DIN; ++i) m[i] = Mg[i * 240 + tx];
        for (int nl = 0; nl < nT; ++nl) {
            const float* xf = (const float*)xin + (size_t)(n0 + nl) * DIN;
            const u16*   xb = (const u16*)xin + (size_t)(n0 + nl) * DIN;
            float acc = 0.f;
#pragma unroll
            for (int i = 0; i < DIN; ++i)
                acc += (RAW ? xf[i] : b2f(xb[i])) * m[i];
            y[nl * 240 + tx] = acc;
        }
    }
    __syncthreads();
    int j0 = soff[n0], j1 = soff[n0 + nT];
    if (tx < 240) {
        int o = tx % 20, grp = tx / 20;
        for (int jj = j0 + grp; jj < j1; jj += 12) {
            int sl = srcP[jj] - n0;
            const u16* er = eaP + (size_t)jj * D_E;
            float mv = y[sl * 240 + 220 + o];
#pragma unroll
            for (int k = 0; k < D_E; ++k) mv += b2f(er[k]) * y[sl * 240 + k * HD + o];
            msg[(size_t)jj * 20 + o] = f2b(mv);
        }
    }
}

// NNConv reduce (round-14): gather msg + x@root + bias + relu, coalesced hout.
template <int DIN, bool RAW>
__global__ __launch_bounds__(256) void nnconv_reduce(
    const void* __restrict__ xin, const float* __restrict__ root,
    const float* __restrict__ bias, const int* __restrict__ doff,
    const int* __restrict__ dslot, const u16* __restrict__ msg,
    u16* __restrict__ hout) {
    __shared__ float Rl[DIN * HD + HD];
    for (int t = threadIdx.x; t < DIN * HD; t += 256) Rl[t] = root[t];
    if (threadIdx.x < HD) Rl[DIN * HD + threadIdx.x] = bias[threadIdx.x];
    __syncthreads();
    int t = blockIdx.x * 256 + threadIdx.x;
    if (t >= N_ATOMS * HD) return;
    int n = t / HD, o = t % HD;
    float acc = Rl[DIN * HD + o];
    int j1 = doff[n + 1];
    for (int j = doff[n]; j < j1; ++j)
        acc += b2f(msg[(size_t)dslot[j] * 20 + o]);
    const float* xf = (const float*)xin + (size_t)n * DIN;
    const u16*   xb = (const u16*)xin + (size_t)n * DIN;
#pragma unroll
    for (int i = 0; i < DIN; ++i)
        acc += (RAW ? xf[i] : b2f(xb[i])) * Rl[i * HD + o];
    hout[t] = f2b(fmaxf(acc, 0.f));
}

// aa gather: label-CSR segmented sum of h3
__global__ __launch_bounds__(256) void aa_gather(
    const u16* __restrict__ h3, const int* __restrict__ loff,
    const int* __restrict__ lnid, float* __restrict__ aa) {
    int t = blockIdx.x * 256 + threadIdx.x;
    if (t >= N_AMINO * HD) return;
    int m = t / HD, o = t % HD;
    float s = 0.f;
    int j1 = loff[m + 1];
    for (int j = loff[m]; j < j1; ++j)
        s += b2f(h3[(size_t)lnid[j] * HD + o]);
    aa[m * 28 + o] = s;
}

// ---------------------------------------------------------------------------
// ARMA gemm28: H(bf16) = aa @ W[k], W + aa-tile in LDS.
__global__ __launch_bounds__(256) void arma_gemm28(
    const float* __restrict__ A, const float* __restrict__ W, size_t wstride,
    u16* __restrict__ H, size_t hstride) {
    __shared__ float Wl[28 * 128];
    __shared__ float Aas[16][28];
    int tx = threadIdx.x;
    const float* Wk = W + blockIdx.y * wstride;
    int n0 = blockIdx.x * 16;
    for (int i = tx; i < 28 * 128; i += 256) Wl[i] = Wk[i];
    for (int i = tx; i < 16 * 28; i += 256)
        Aas[i / 28][i % 28] = A[(size_t)(n0 + i / 28) * 28 + i % 28];
    __syncthreads();
    int nl = tx >> 4, c0 = (tx & 15) * 8;
    u16* Hk = H + blockIdx.y * hstride;
    float acc[8];
#pragma unroll
    for (int j = 0; j < 8; ++j) acc[j] = 0.f;
    for (int f = 0; f < 28; ++f) {
        float av = Aas[nl][f];
        const float* wr = &Wl[f * 128 + c0];
        float4 w0 = *(const float4*)wr, w1 = *(const float4*)(wr + 4);
        acc[0] += av * w0.x; acc[1] += av * w0.y; acc[2] += av * w0.z; acc[3] += av * w0.w;
        acc[4] += av * w1.x; acc[5] += av * w1.y; acc[6] += av * w1.z; acc[7] += av * w1.w;
    }
    uint4 pk;
    pk.x = (u32)f2b(acc[0]) | ((u32)f2b(acc[1]) << 16);
    pk.y = (u32)f2b(acc[2]) | ((u32)f2b(acc[3]) << 16);
    pk.z = (u32)f2b(acc[4]) | ((u32)f2b(acc[5]) << 16);
    pk.w = (u32)f2b(acc[6]) | ((u32)f2b(acc[7]) << 16);
    *(uint4*)(Hk + (size_t)(n0 + nl) * HA + c0) = pk;
}

// ARMA gemm via MFMA bf16: H(bf16) = O_bf16 @ Wp_bf16.
__global__ __launch_bounds__(256) void arma_gemm_mf(
    const u16* __restrict__ Obh, size_t astride,
    const u16* __restrict__ Wp,
    u16* __restrict__ H, size_t hstride) {
    int wave = threadIdx.x >> 6, lane = threadIdx.x & 63;
    int k = blockIdx.y;
    const u16* A = Obh + (size_t)k * astride;
    const u16* W = Wp + (size_t)k * 16384;
    u16* Hk = H + (size_t)k * hstride;
    int n0 = (blockIdx.x * 4 + wave) * 16;
    int m = lane & 15, q = lane >> 4;
    short8 aF[4];
#pragma unroll
    for (int kb = 0; kb < 4; ++kb)
        aF[kb] = *(const short8*)(A + (size_t)(n0 + m) * HA + kb * 32 + q * 8);
#pragma unroll
    for (int ct = 0; ct < 8; ++ct) {
        int c0 = ct * 16;
        f32x4 acc = {0.f, 0.f, 0.f, 0.f};
#pragma unroll
        for (int kb = 0; kb < 4; ++kb) {
            short8 bF = *(const short8*)(W + (size_t)((kb * 128 + c0 + m) * 32 + q * 8));
            acc = __builtin_amdgcn_mfma_f32_16x16x32_bf16(aF[kb], bF, acc, 0, 0, 0);
        }
#pragma unroll
        for (int r = 0; r < 4; ++r)
            Hk[(size_t)(n0 + q * 4 + r) * HA + c0 + m] = f2b(acc[r]);
    }
}

// ARMA out: gather (bf16 H, uint4 loads) + root-gemm (LDS) + relu; O bf16.
__global__ __launch_bounds__(256) void arma_out(
    const u16* __restrict__ H, size_t hstride,
    const float* __restrict__ aa,
    const float* __restrict__ rw, size_t rstride,
    const float* __restrict__ bw, size_t bstride,
    const int* __restrict__ aei, const int* __restrict__ aoff,
    const int* __restrict__ aeid, const float* __restrict__ nrm,
    u16* __restrict__ O, size_t ostride) {
    __shared__ float Rw[28 * 128];
    __shared__ float Bw[128];
    __shared__ float Aas[16][28];
    int tx = threadIdx.x;
    const float* rwk = rw + blockIdx.y * rstride;
    const float* bwk = bw + blockIdx.y * bstride;
    int n0 = blockIdx.x * 16;
    for (int i = tx; i < 28 * 128; i += 256) Rw[i] = rwk[i];
    if (tx < 128) Bw[tx] = bwk[tx];
    for (int i = tx; i < 16 * 28; i += 256)
        Aas[i / 28][i % 28] = aa[(size_t)(n0 + i / 28) * 28 + i % 28];
    __syncthreads();
    int nl = tx >> 4, c0 = (tx & 15) * 8;
    int n = n0 + nl;
    const u16* Hk = H + blockIdx.y * hstride;
    u16* Ok = O + blockIdx.y * ostride;
    float acc[8];
#pragma unroll
    for (int j = 0; j < 8; ++j) acc[j] = Bw[c0 + j];
    int j1 = aoff[n + 1];
    for (int jj = aoff[n]; jj < j1; ++jj) {
        int e = aeid[jj], s = aei[e];
        float nm = nrm[e];
        uint4 hv = *(const uint4*)(Hk + (size_t)s * HA + c0);
        acc[0] += nm * b2f((u16)(hv.x & 0xffff));
        acc[1] += nm * b2f((u16)(hv.x >> 16));
        acc[2] += nm * b2f((u16)(hv.y & 0xffff));
        acc[3] += nm * b2f((u16)(hv.y >> 16));
        acc[4] += nm * b2f((u16)(hv.z & 0xffff));
        acc[5] += nm * b2f((u16)(hv.z >> 16));
        acc[6] += nm * b2f((u16)(hv.w & 0xffff));
        acc[7] += nm * b2f((u16)(hv.w >> 16));
    }
    for (int f = 0; f < 28; ++f) {
        float av = Aas[nl][f];
        const float* wr = &Rw[f * 128 + c0];
        float4 w0 = *(const float4*)wr, w1 = *(const float4*)(wr + 4);
        acc[0] += av * w0.x; acc[1] += av * w0.y; acc[2] += av * w0.z; acc[3] += av * w0.w;
        acc[4] += av * w1.x; acc[5] += av * w1.y; acc[6] += av * w1.z; acc[7] += av * w1.w;
    }
#pragma unroll
    for (int j = 0; j < 8; ++j) acc[j] = fmaxf(acc[j], 0.f);
    uint4 pk;
    pk.x = (u32)f2b(acc[0]) | ((u32)f2b(acc[1]) << 16);
    pk.y = (u32)f2b(acc[2]) | ((u32)f2b(acc[3]) << 16);
    pk.z = (u32)f2b(acc[4]) | ((u32)f2b(acc[5]) << 16);
    pk.w = (u32)f2b(acc[6]) | ((u32)f2b(acc[7]) << 16);
    *(uint4*)(Ok + (size_t)n * HA + c0) = pk;
}

// ---------------------------------------------------------------------------
// head2: fused readout (sorted amino_batch segmented sum over bf16 O) + MLP.
__global__ __launch_bounds__(256) void head2(
    const u16* __restrict__ O, size_t kstride, const int* __restrict__ bat,
    const float* __restrict__ l1w, const float* __restrict__ l1b,
    const float* __restrict__ l2w, const float* __restrict__ l2b,
    const float* __restrict__ l3w, const float* __restrict__ l3b,
    const float* __restrict__ l4w, const float* __restrict__ l4b,
    float* __restrict__ outp) {
    __shared__ float sg[HA], sp1[F1], sp2[F2], sp3[F3];
    int b = blockIdx.x, tx = threadIdx.x;
    int lo = 0, hi = N_AMINO;
    while (lo < hi) { int mid = (lo + hi) >> 1; if (bat[mid] < b) lo = mid + 1; else hi = mid; }
    int s = lo;
    lo = 0; hi = N_AMINO;
    while (lo < hi) { int mid = (lo + hi) >> 1; if (bat[mid] < b + 1) lo = mid + 1; else hi = mid; }
    int e = lo;
    if (tx < HA) {
        float acc = 0.f;
        for (int n = s; n < e; ++n)
            acc += b2f(O[(size_t)n * HA + tx]) + b2f(O[kstride + (size_t)n * HA + tx])
                 + b2f(O[2 * kstride + (size_t)n * HA + tx]);
        sg[tx] = acc * (1.f / 3.f);
    }
    __syncthreads();
    {   float acc = l1b[tx];
        for (int f = 0; f < HA; ++f) acc += sg[f] * l1w[f * F1 + tx];
        sp1[tx] = fmaxf(acc, 0.f); }
    __syncthreads();
    if (tx < F2) {
        float acc = l2b[tx];
        for (int f = 0; f < F1; ++f) acc += sp1[f] * l2w[f * F2 + tx];
        sp2[tx] = fmaxf(acc, 0.f); }
    __syncthreads();
    if (tx < F3) {
        float acc = l3b[tx];
        for (int f = 0; f < F2; ++f) acc += sp2[f] * l3w[f * F3 + tx];
        sp3[tx] = fmaxf(acc, 0.f); }
    __syncthreads();
    if (tx < 64) {
        float p = sp3[tx] * l4w[tx];
        for (int off = 32; off > 0; off >>= 1) p += __shfl_down(p, off, 64);
        if (tx == 0) outp[b] = p + l4b[0];
    }
}

// ---------------------------------------------------------------------------
// Workspace (<= 34,348,288 B, proven available).
#define OFF_M1    ((size_t)0)
#define OFF_M2    ((size_t)38400)
#define OFF_M3    ((size_t)57600)
#define OFF_AOFF  ((size_t)76800)
#define OFF_AEID  ((size_t)118016)
#define OFF_NRM   ((size_t)199936)
#define OFF_AA    ((size_t)281856)
#define OFF_HA    ((size_t)2891008)
#define OFF_HB    ((size_t)6891008)
#define OFF_MSG   ((size_t)10891008)
#define OFF_SOFF  ((size_t)18891008)
#define OFF_DOFF  ((size_t)19291136)
#define OFF_DSLOT ((size_t)19691264)
#define OFF_LOFF  ((size_t)20491264)
#define OFF_LNID  ((size_t)20532480)
#define OFF_CS    ((size_t)20932480)
#define OFF_CD    ((size_t)21332480)
#define OFF_CA    ((size_t)21732480)
#define OFF_CL    ((size_t)21773440)
#define OFF_US    ((size_t)21814400)
#define OFF_UD    ((size_t)22214400)
#define OFF_UA    ((size_t)22614400)
#define OFF_UL    ((size_t)22655360)
#define OFF_BSUM  ((size_t)22696320)
#define OFF_EAP   ((size_t)22697216)      // bf16 4,400,000 -> 27,097,216
#define OFF_SRCP  ((size_t)27097216)      // 800,000 -> 27,897,216
#define OFF_WP    ((size_t)27897216)      // 589,824 -> 28,487,040
// ARMA overlay: H bf16 2,891,008..10,755,328; O bf16 18,619,648..26,483,968.
#define OFF_ARH   ((size_t)2891008)
#define OFF_ARO   ((size_t)18619648)

extern "C" void kernel_launch(void* const* d_in, const int* in_sizes, int n_in,
                              void* d_out, int out_size, void* d_ws, size_t ws_size,
                              hipStream_t stream) {
    (void)in_sizes; (void)n_in; (void)out_size; (void)ws_size;
    const float* x   = (const float*)d_in[0];
    const int*   ei  = (const int*)d_in[1];
    const float* ea  = (const float*)d_in[2];
    const int*   lbl = (const int*)d_in[3];
    const float* af  = (const float*)d_in[4];
    const int*   aei = (const int*)d_in[5];
    const int*   bat = (const int*)d_in[6];
    const float* nn1w = (const float*)d_in[7];  const float* nn1b = (const float*)d_in[8];
    const float* rt1  = (const float*)d_in[9];  const float* b1   = (const float*)d_in[10];
    const float* nn2w = (const float*)d_in[11]; const float* nn2b = (const float*)d_in[12];
    const float* rt2  = (const float*)d_in[13]; const float* b2   = (const float*)d_in[14];
    const float* nn3w = (const float*)d_in[15]; const float* nn3b = (const float*)d_in[16];
    const float* rt3  = (const float*)d_in[17]; const float* b3   = (const float*)d_in[18];
    const float* ai   = (const float*)d_in[19]; const float* aw   = (const float*)d_in[20];
    const float* arw  = (const float*)d_in[21]; const float* abi  = (const float*)d_in[22];
    const float* l1w  = (const float*)d_in[23]; const float* l1b  = (const float*)d_in[24];
    const float* l2w  = (const float*)d_in[25]; const float* l2b  = (const float*)d_in[26];
    const float* l3w  = (const float*)d_in[27]; const float* l3b  = (const float*)d_in[28];
    const float* l4w  = (const float*)d_in[29]; const float* l4b  = (const float*)d_in[30];
    float* outp = (float*)d_out;

    char* ws = (char*)d_ws;
    float* M1    = (float*)(ws + OFF_M1);
    float* M2    = (float*)(ws + OFF_M2);
    float* M3    = (float*)(ws + OFF_M3);
    int*   aoff  = (int*)(ws + OFF_AOFF);
    int*   aeid  = (int*)(ws + OFF_AEID);
    float* nrm   = (float*)(ws + OFF_NRM);
    float* aa    = (float*)(ws + OFF_AA);
    u16*   hA    = (u16*)(ws + OFF_HA);
    u16*   hB    = (u16*)(ws + OFF_HB);
    u16*   msg   = (u16*)(ws + OFF_MSG);
    int*   soff  = (int*)(ws + OFF_SOFF);
    int*   doff  = (int*)(ws + OFF_DOFF);
    int*   dslot = (int*)(ws + OFF_DSLOT);
    int*   loff  = (int*)(ws + OFF_LOFF);
    int*   lnid  = (int*)(ws + OFF_LNID);
    int*   cs    = (int*)(ws + OFF_CS);
    int*   cd    = (int*)(ws + OFF_CD);
    int*   ca    = (int*)(ws + OFF_CA);
    int*   cl    = (int*)(ws + OFF_CL);
    int*   us    = (int*)(ws + OFF_US);
    int*   ud    = (int*)(ws + OFF_UD);
    int*   ua    = (int*)(ws + OFF_UA);
    int*   ul    = (int*)(ws + OFF_UL);
    int*   bsum  = (int*)(ws + OFF_BSUM);
    u16*   eaP   = (u16*)(ws + OFF_EAP);
    int*   srcP  = (int*)(ws + OFF_SRCP);
    u16*   Wp    = (u16*)(ws + OFF_WP);
    u16*   Hb    = (u16*)(ws + OFF_ARH);
    u16*   Obh   = (u16*)(ws + OFF_ARO);

    const int* esrc = ei;
    const int* edst = ei + E_ATOMS;
    const int* adst = aei + E_AMINO;

    // prep
    k_prep0<<<(PREP0_N + 255) / 256, 256, 0, stream>>>(
        nn1w, nn1b, nn2w, nn2b, nn3w, nn3b, M1, M2, M3, af, aa, cs, cd, ca, cl);
    k_cvtwp<<<((TL - 1) * KS * 16384 + 255) / 256, 256, 0, stream>>>(aw, Wp);
    k_csr_count<<<(2 * E_ATOMS + E_AMINO + N_ATOMS + 255) / 256, 256, 0, stream>>>(
        esrc, edst, adst, lbl, cs, cd, ca, cl);
    k_scan1<<<2 * NBS + 2 * NBA, 256, 0, stream>>>(cs, soff, cd, doff, ca, aoff, cl, loff, bsum);
    k_scan2<<<4, 128, 0, stream>>>(bsum, soff, doff, aoff, loff);
    k_scan3<<<2 * NBS + 2 * NBA, 256, 0, stream>>>(soff, doff, aoff, loff, bsum, us, ud, ua, ul);
    k_csr_fill<<<(E_ATOMS + 2 * E_AMINO + N_ATOMS + 255) / 256, 256, 0, stream>>>(
        esrc, edst, ea, us, srcP, eaP, ud, dslot, aei, ua, aeid, aoff, nrm, lbl, ul, lnid);

    // NNConv (round-14 structure, bf16 eaP)
    const int GT = (N_ATOMS + TILE - 1) / TILE;   // 3125
    const int GF = (N_ATOMS * HD + 255) / 256;    // 7813
    nnconv_edge3<DIN0, true ><<<GT, 256, 0, stream>>>(x,  eaP, srcP, soff, M1, msg);
    nnconv_reduce<DIN0, true ><<<GF, 256, 0, stream>>>(x,  rt1, b1, doff, dslot, msg, hA);
    nnconv_edge3<HD,   false><<<GT, 256, 0, stream>>>(hA, eaP, srcP, soff, M2, msg);
    nnconv_reduce<HD,   false><<<GF, 256, 0, stream>>>(hA, rt2, b2, doff, dslot, msg, hB);
    nnconv_edge3<HD,   false><<<GT, 256, 0, stream>>>(hB, eaP, srcP, soff, M3, msg);
    nnconv_reduce<HD,   false><<<GF, 256, 0, stream>>>(hB, rt3, b3, doff, dslot, msg, hA);
    aa_gather<<<(N_AMINO * HD + 255) / 256, 256, 0, stream>>>(hA, loff, lnid, aa);

    // ARMA: K-parallel, T layers; bf16 H/O, MFMA gemms
    const size_t KH = (size_t)N_AMINO * HA;
    for (int t = 0; t < TL; ++t) {
        if (t == 0)
            arma_gemm28<<<dim3(640, KS), 256, 0, stream>>>(aa, ai, 28 * HA, Hb, KH);
        else
            arma_gemm_mf<<<dim3(160, KS), 256, 0, stream>>>(
                Obh, KH, Wp + (size_t)(t - 1) * KS * 16384, Hb, KH);
        arma_out<<<dim3(640, KS), 256, 0, stream>>>(
            Hb, KH, aa, arw + (size_t)t * KS * 28 * HA, 28 * HA,
            abi + (size_t)t * KS * HA, HA, aei, aoff, aeid, nrm, Obh, KH);
    }

    head2<<<NGRAPH, 256, 0, stream>>>(Obh, KH, bat, l1w, l1b, l2w, l2b,
                                      l3w, l3b, l4w, l4b, outp);
}

// Round 18
// 618.079 us; speedup vs baseline: 1.1701x; 1.0494x over previous
//
#include <hip/hip_runtime.h>

#define N_ATOMS 100000
#define E_ATOMS 200000
#define N_AMINO 10240
#define E_AMINO 20480
#define NGRAPH 512
#define DIN0 40
#define D_E 11
#define HD 20
#define D_AA 8
#define HA 128
#define KS 3
#define TL 7
#define F1 256
#define F2 128
#define F3 64
#define TILE 32
#define EAW 12   // padded eaP row (u16), 24 B, 8-byte aligned

typedef unsigned short u16;
typedef unsigned int u32;
typedef __attribute__((ext_vector_type(8))) short short8;
typedef __attribute__((ext_vector_type(4))) float f32x4;

__device__ __forceinline__ float b2f(u16 u) {
    union { u32 i; float f; } v; v.i = ((u32)u) << 16; return v.f;
}
__device__ __forceinline__ u16 f2b(float f) {
    union { float f; u32 i; } v; v.f = f;
    u32 x = v.i;
    return (u16)((x + (((x >> 16) & 1u) + 0x7fffu)) >> 16);
}

// ---------------------------------------------------------------------------
// prep0: M matrices (240 cols: W|b) + aa feature columns + zero CSR counts.
__global__ __launch_bounds__(256) void k_prep0(
    const float* __restrict__ w1, const float* __restrict__ b1,
    const float* __restrict__ w2, const float* __restrict__ b2,
    const float* __restrict__ w3, const float* __restrict__ b3,
    float* __restrict__ M1, float* __restrict__ M2, float* __restrict__ M3,
    const float* __restrict__ af, float* __restrict__ aa,
    int* __restrict__ cs, int* __restrict__ cd,
    int* __restrict__ ca, int* __restrict__ cl) {
    int t = blockIdx.x * 256 + threadIdx.x;
    if (t < 9600) {
        int i = t / 240, c = t % 240;
        M1[t] = (c < 220) ? w1[(c / 20) * 800 + i * 20 + (c % 20)] : b1[i * 20 + (c - 220)];
    } else if (t < 14400) {
        int tt = t - 9600, i = tt / 240, c = tt % 240;
        M2[tt] = (c < 220) ? w2[(c / 20) * 400 + i * 20 + (c % 20)] : b2[i * 20 + (c - 220)];
    } else if (t < 19200) {
        int tt = t - 14400, i = tt / 240, c = tt % 240;
        M3[tt] = (c < 220) ? w3[(c / 20) * 400 + i * 20 + (c % 20)] : b3[i * 20 + (c - 220)];
    } else if (t < 19200 + N_AMINO * D_AA) {
        int idx = t - 19200, m = idx / D_AA, j = idx % D_AA;
        aa[m * 28 + HD + j] = af[idx];
    } else {
        int z = t - 19200 - N_AMINO * D_AA;
        if (z < N_ATOMS) cs[z] = 0;
        else if (z < 2 * N_ATOMS) cd[z - N_ATOMS] = 0;
        else if (z < 2 * N_ATOMS + N_AMINO) ca[z - 2 * N_ATOMS] = 0;
        else if (z < 2 * N_ATOMS + 2 * N_AMINO) cl[z - 2 * N_ATOMS - N_AMINO] = 0;
    }
}
#define PREP0_N (19200 + N_AMINO * D_AA + 2 * N_ATOMS + 2 * N_AMINO)

// Pack arma_w into MFMA B-fragment order, bf16.
__global__ __launch_bounds__(256) void k_cvtwp(const float* __restrict__ aw,
                                               u16* __restrict__ Wp) {
    int g = blockIdx.x * 256 + threadIdx.x;
    if (g >= (TL - 1) * KS * 16384) return;
    int mat = g >> 14, r = g & 16383;
    int kb = r >> 12, rem = r & 4095;
    int c = rem >> 5, qj = rem & 31;
    Wp[g] = f2b(aw[(size_t)mat * 16384 + (size_t)(kb * 32 + qj) * HA + c]);
}

// ---------------------------------------------------------------------------
#define NBS 98
#define NBA 10

__global__ __launch_bounds__(256) void k_csr_count(
    const int* __restrict__ esrc, const int* __restrict__ edst,
    const int* __restrict__ adst, const int* __restrict__ lbl,
    int* __restrict__ cs, int* __restrict__ cd,
    int* __restrict__ ca, int* __restrict__ cl) {
    int t = blockIdx.x * 256 + threadIdx.x;
    if (t < E_ATOMS) atomicAdd(cs + esrc[t], 1);
    else if (t < 2 * E_ATOMS) atomicAdd(cd + edst[t - E_ATOMS], 1);
    else if (t < 2 * E_ATOMS + E_AMINO) atomicAdd(ca + adst[t - 2 * E_ATOMS], 1);
    else if (t < 2 * E_ATOMS + E_AMINO + N_ATOMS) atomicAdd(cl + lbl[t - 2 * E_ATOMS - E_AMINO], 1);
}
__device__ __forceinline__ void seg_decode(int bx, int* blk, int* n, int* which) {
    if (bx < NBS)            { *which = 0; *blk = bx;             *n = N_ATOMS; }
    else if (bx < 2 * NBS)   { *which = 1; *blk = bx - NBS;       *n = N_ATOMS; }
    else if (bx < 2 * NBS + NBA) { *which = 2; *blk = bx - 2 * NBS; *n = N_AMINO; }
    else                     { *which = 3; *blk = bx - 2 * NBS - NBA; *n = N_AMINO; }
}
__global__ __launch_bounds__(256) void k_scan1(
    const int* __restrict__ cs, int* __restrict__ soff,
    const int* __restrict__ cd, int* __restrict__ doff,
    const int* __restrict__ ca, int* __restrict__ aoff,
    const int* __restrict__ cl, int* __restrict__ loff,
    int* __restrict__ bsum) {
    int blk, n, which;
    seg_decode(blockIdx.x, &blk, &n, &which);
    const int* c = which == 0 ? cs : which == 1 ? cd : which == 2 ? ca : cl;
    int* o = which == 0 ? soff : which == 1 ? doff : which == 2 ? aoff : loff;
    int tx = threadIdx.x, lane = tx & 63, w = tx >> 6;
    int i0 = blk * 1024 + tx * 4;
    int v[4];
#pragma unroll
    for (int q = 0; q < 4; ++q) v[q] = (i0 + q < n) ? c[i0 + q] : 0;
    int s = v[0] + v[1] + v[2] + v[3];
    int inc = s;
#pragma unroll
    for (int d = 1; d < 64; d <<= 1) {
        int u = __shfl_up(inc, d, 64);
        if (lane >= d) inc += u;
    }
    __shared__ int wsum[4];
    if (lane == 63) wsum[w] = inc;
    __syncthreads();
    int wo = 0;
    for (int i = 0; i < w; ++i) wo += wsum[i];
    int run = wo + inc - s;
#pragma unroll
    for (int q = 0; q < 4; ++q) {
        if (i0 + q < n) o[i0 + q] = run;
        run += v[q];
    }
    if (tx == 255) bsum[blockIdx.x] = wo + inc;
}
__global__ __launch_bounds__(128) void k_scan2(
    int* __restrict__ bsum, int* __restrict__ soff, int* __restrict__ doff,
    int* __restrict__ aoff, int* __restrict__ loff) {
    int bx = blockIdx.x;
    int nb   = (bx < 2) ? NBS : NBA;
    int base = (bx == 0) ? 0 : (bx == 1) ? NBS : (bx == 2) ? 2 * NBS : 2 * NBS + NBA;
    int* b = bsum + base;
    int tx = threadIdx.x, lane = tx & 63;
    int v = (tx < nb) ? b[tx] : 0;
    int inc = v;
#pragma unroll
    for (int d = 1; d < 64; d <<= 1) {
        int u = __shfl_up(inc, d, 64);
        if (lane >= d) inc += u;
    }
    __shared__ int w0;
    if (tx == 63) w0 = inc;
    __syncthreads();
    int excl = inc - v + ((tx >= 64) ? w0 : 0);
    if (tx < nb) b[tx] = excl;
    if (tx == nb - 1) {
        int tot = excl + v;
        if (bx == 0) soff[N_ATOMS] = tot;
        else if (bx == 1) doff[N_ATOMS] = tot;
        else if (bx == 2) aoff[N_AMINO] = tot;
        else loff[N_AMINO] = tot;
    }
}
__global__ __launch_bounds__(256) void k_scan3(
    int* __restrict__ soff, int* __restrict__ doff,
    int* __restrict__ aoff, int* __restrict__ loff,
    const int* __restrict__ bsum,
    int* __restrict__ us, int* __restrict__ ud,
    int* __restrict__ ua, int* __restrict__ ul) {
    int blk, n, which;
    seg_decode(blockIdx.x, &blk, &n, &which);
    int* o = which == 0 ? soff : which == 1 ? doff : which == 2 ? aoff : loff;
    int* cu = which == 0 ? us : which == 1 ? ud : which == 2 ? ua : ul;
    int add = bsum[blockIdx.x];
    int i0 = blk * 1024 + threadIdx.x * 4;
#pragma unroll
    for (int q = 0; q < 4; ++q)
        if (i0 + q < n) { int val = o[i0 + q] + add; o[i0 + q] = val; cu[i0 + q] = val; }
}
// fill: src slots -> srcP/eaP(bf16, padded to 12), dst->slot, amino eids+nrm,
// label->node
__global__ __launch_bounds__(256) void k_csr_fill(
    const int* __restrict__ esrc, const int* __restrict__ edst,
    const float* __restrict__ ea,
    int* __restrict__ us, int* __restrict__ srcP, u16* __restrict__ eaP,
    int* __restrict__ ud, int* __restrict__ dslot,
    const int* __restrict__ aei, int* __restrict__ ua, int* __restrict__ aeid,
    const int* __restrict__ aoff, float* __restrict__ nrm,
    const int* __restrict__ lbl, int* __restrict__ ul, int* __restrict__ lnid) {
    int t = blockIdx.x * 256 + threadIdx.x;
    if (t < E_ATOMS) {
        int jj = atomicAdd(us + esrc[t], 1);
        srcP[jj] = esrc[t];
        const float* e0 = ea + (size_t)t * D_E;
        u16* e1 = eaP + (size_t)jj * EAW;
#pragma unroll
        for (int k = 0; k < D_E; ++k) e1[k] = f2b(e0[k]);
        e1[D_E] = 0;
        int p = atomicAdd(ud + edst[t], 1);
        dslot[p] = jj;
    } else if (t < E_ATOMS + E_AMINO) {
        int e = t - E_ATOMS;
        int p = atomicAdd(ua + aei[E_AMINO + e], 1);
        aeid[p] = e;
    } else if (t < E_ATOMS + 2 * E_AMINO) {
        int e = t - E_ATOMS - E_AMINO;
        int s = aei[e], d = aei[E_AMINO + e];
        int ds = aoff[s + 1] - aoff[s], dd = aoff[d + 1] - aoff[d];
        float a = ds > 0 ? rsqrtf((float)ds) : 0.f;
        float b = dd > 0 ? rsqrtf((float)dd) : 0.f;
        nrm[e] = a * b;
    } else if (t < E_ATOMS + 2 * E_AMINO + N_ATOMS) {
        int n = t - E_ATOMS - 2 * E_AMINO;
        int p = atomicAdd(ul + lbl[n], 1);
        lnid[p] = n;
    }
}

// ---------------------------------------------------------------------------
// NNConv edge: 32-node tiles. x tile staged in LDS (coalesced once), phase 1
// reads xs via LDS broadcast. Phase 2: uint2-vectorized eaP. bf16 msg.
template <int DIN, bool RAW>
__global__ __launch_bounds__(256) void nnconv_edge6(
    const void* __restrict__ xin, const u16* __restrict__ eaP,
    const int* __restrict__ srcP, const int* __restrict__ soff,
    const float* __restrict__ Mg, u16* __restrict__ msg) {
    __shared__ float y[TILE * 240];
    __shared__ float xs[TILE * DIN];
    int tx = threadIdx.x;
    int n0 = blockIdx.x * TILE;          // N_ATOMS % TILE == 0
    // stage x tile (coalesced)
    for (int i = tx; i < TILE * DIN; i += 256)
        xs[i] = RAW ? ((const float*)xin)[(size_t)n0 * DIN + i]
                    : b2f(((const u16*)xin)[(size_t)n0 * DIN + i]);
    __syncthreads();
    if (tx < 240) {
        float m[DIN];
#pragma unroll
        for (int i = 0; i < DIN; ++i) m[i] = Mg[i * 240 + tx];
        for (int nl = 0; nl < TILE; ++nl) {
            const float* xr = &xs[nl * DIN];
            float acc = 0.f;
#pragma unroll
            for (int i = 0; i < DIN; ++i) acc += xr[i] * m[i];
            y[nl * 240 + tx] = acc;
        }
    }
    __syncthreads();
    int j0 = soff[n0], j1 = soff[n0 + TILE];
    if (tx < 240) {
        int o = tx % 20, grp = tx / 20;
        for (int jj = j0 + grp; jj < j1; jj += 12) {
            int sl = srcP[jj] - n0;
            const u16* er = eaP + (size_t)jj * EAW;
            uint2 p0 = *(const uint2*)er;
            uint2 p1 = *(const uint2*)(er + 4);
            uint2 p2 = *(const uint2*)(er + 8);
            float ev[D_E];
            ev[0] = b2f((u16)(p0.x & 0xffff)); ev[1] = b2f((u16)(p0.x >> 16));
            ev[2] = b2f((u16)(p0.y & 0xffff)); ev[3] = b2f((u16)(p0.y >> 16));
            ev[4] = b2f((u16)(p1.x & 0xffff)); ev[5] = b2f((u16)(p1.x >> 16));
            ev[6] = b2f((u16)(p1.y & 0xffff)); ev[7] = b2f((u16)(p1.y >> 16));
            ev[8] = b2f((u16)(p2.x & 0xffff)); ev[9] = b2f((u16)(p2.x >> 16));
            ev[10] = b2f((u16)(p2.y & 0xffff));
            const float* yr = &y[sl * 240];
            float mv = yr[220 + o];
#pragma unroll
            for (int k = 0; k < D_E; ++k) mv += ev[k] * yr[k * HD + o];
            msg[(size_t)jj * 20 + o] = f2b(mv);
        }
    }
}

// NNConv reduce: gather msg + x@root + bias + relu, coalesced hout.
template <int DIN, bool RAW>
__global__ __launch_bounds__(256) void nnconv_reduce(
    const void* __restrict__ xin, const float* __restrict__ root,
    const float* __restrict__ bias, const int* __restrict__ doff,
    const int* __restrict__ dslot, const u16* __restrict__ msg,
    u16* __restrict__ hout) {
    __shared__ float Rl[DIN * HD + HD];
    for (int t = threadIdx.x; t < DIN * HD; t += 256) Rl[t] = root[t];
    if (threadIdx.x < HD) Rl[DIN * HD + threadIdx.x] = bias[threadIdx.x];
    __syncthreads();
    int t = blockIdx.x * 256 + threadIdx.x;
    if (t >= N_ATOMS * HD) return;
    int n = t / HD, o = t % HD;
    float acc = Rl[DIN * HD + o];
    int j1 = doff[n + 1];
    for (int j = doff[n]; j < j1; ++j)
        acc += b2f(msg[(size_t)dslot[j] * 20 + o]);
    const float* xf = (const float*)xin + (size_t)n * DIN;
    const u16*   xb = (const u16*)xin + (size_t)n * DIN;
#pragma unroll
    for (int i = 0; i < DIN; ++i)
        acc += (RAW ? xf[i] : b2f(xb[i])) * Rl[i * HD + o];
    hout[t] = f2b(fmaxf(acc, 0.f));
}

// aa gather: label-CSR segmented sum of h3
__global__ __launch_bounds__(256) void aa_gather(
    const u16* __restrict__ h3, const int* __restrict__ loff,
    const int* __restrict__ lnid, float* __restrict__ aa) {
    int t = blockIdx.x * 256 + threadIdx.x;
    if (t >= N_AMINO * HD) return;
    int m = t / HD, o = t % HD;
    float s = 0.f;
    int j1 = loff[m + 1];
    for (int j = loff[m]; j < j1; ++j)
        s += b2f(h3[(size_t)lnid[j] * HD + o]);
    aa[m * 28 + o] = s;
}

// ---------------------------------------------------------------------------
// ARMA gemm28: H(bf16) = aa @ W[k], W + aa-tile in LDS.
__global__ __launch_bounds__(256) void arma_gemm28(
    const float* __restrict__ A, const float* __restrict__ W, size_t wstride,
    u16* __restrict__ H, size_t hstride) {
    __shared__ float Wl[28 * 128];
    __shared__ float Aas[16][28];
    int tx = threadIdx.x;
    const float* Wk = W + blockIdx.y * wstride;
    int n0 = blockIdx.x * 16;
    for (int i = tx; i < 28 * 128; i += 256) Wl[i] = Wk[i];
    for (int i = tx; i < 16 * 28; i += 256)
        Aas[i / 28][i % 28] = A[(size_t)(n0 + i / 28) * 28 + i % 28];
    __syncthreads();
    int nl = tx >> 4, c0 = (tx & 15) * 8;
    u16* Hk = H + blockIdx.y * hstride;
    float acc[8];
#pragma unroll
    for (int j = 0; j < 8; ++j) acc[j] = 0.f;
    for (int f = 0; f < 28; ++f) {
        float av = Aas[nl][f];
        const float* wr = &Wl[f * 128 + c0];
        float4 w0 = *(const float4*)wr, w1 = *(const float4*)(wr + 4);
        acc[0] += av * w0.x; acc[1] += av * w0.y; acc[2] += av * w0.z; acc[3] += av * w0.w;
        acc[4] += av * w1.x; acc[5] += av * w1.y; acc[6] += av * w1.z; acc[7] += av * w1.w;
    }
    uint4 pk;
    pk.x = (u32)f2b(acc[0]) | ((u32)f2b(acc[1]) << 16);
    pk.y = (u32)f2b(acc[2]) | ((u32)f2b(acc[3]) << 16);
    pk.z = (u32)f2b(acc[4]) | ((u32)f2b(acc[5]) << 16);
    pk.w = (u32)f2b(acc[6]) | ((u32)f2b(acc[7]) << 16);
    *(uint4*)(Hk + (size_t)(n0 + nl) * HA + c0) = pk;
}

// ARMA gemm via MFMA bf16: H(bf16) = O_bf16 @ Wp_bf16.
__global__ __launch_bounds__(256) void arma_gemm_mf(
    const u16* __restrict__ Obh, size_t astride,
    const u16* __restrict__ Wp,
    u16* __restrict__ H, size_t hstride) {
    int wave = threadIdx.x >> 6, lane = threadIdx.x & 63;
    int k = blockIdx.y;
    const u16* A = Obh + (size_t)k * astride;
    const u16* W = Wp + (size_t)k * 16384;
    u16* Hk = H + (size_t)k * hstride;
    int n0 = (blockIdx.x * 4 + wave) * 16;
    int m = lane & 15, q = lane >> 4;
    short8 aF[4];
#pragma unroll
    for (int kb = 0; kb < 4; ++kb)
        aF[kb] = *(const short8*)(A + (size_t)(n0 + m) * HA + kb * 32 + q * 8);
#pragma unroll
    for (int ct = 0; ct < 8; ++ct) {
        int c0 = ct * 16;
        f32x4 acc = {0.f, 0.f, 0.f, 0.f};
#pragma unroll
        for (int kb = 0; kb < 4; ++kb) {
            short8 bF = *(const short8*)(W + (size_t)((kb * 128 + c0 + m) * 32 + q * 8));
            acc = __builtin_amdgcn_mfma_f32_16x16x32_bf16(aF[kb], bF, acc, 0, 0, 0);
        }
#pragma unroll
        for (int r = 0; r < 4; ++r)
            Hk[(size_t)(n0 + q * 4 + r) * HA + c0 + m] = f2b(acc[r]);
    }
}

// ARMA out: gather (bf16 H, uint4 loads) + root-gemm (LDS) + relu; O bf16.
__global__ __launch_bounds__(256) void arma_out(
    const u16* __restrict__ H, size_t hstride,
    const float* __restrict__ aa,
    const float* __restrict__ rw, size_t rstride,
    const float* __restrict__ bw, size_t bstride,
    const int* __restrict__ aei, const int* __restrict__ aoff,
    const int* __restrict__ aeid, const float* __restrict__ nrm,
    u16* __restrict__ O, size_t ostride) {
    __shared__ float Rw[28 * 128];
    __shared__ float Bw[128];
    __shared__ float Aas[16][28];
    int tx = threadIdx.x;
    const float* rwk = rw + blockIdx.y * rstride;
    const float* bwk = bw + blockIdx.y * bstride;
    int n0 = blockIdx.x * 16;
    for (int i = tx; i < 28 * 128; i += 256) Rw[i] = rwk[i];
    if (tx < 128) Bw[tx] = bwk[tx];
    for (int i = tx; i < 16 * 28; i += 256)
        Aas[i / 28][i % 28] = aa[(size_t)(n0 + i / 28) * 28 + i % 28];
    __syncthreads();
    int nl = tx >> 4, c0 = (tx & 15) * 8;
    int n = n0 + nl;
    const u16* Hk = H + blockIdx.y * hstride;
    u16* Ok = O + blockIdx.y * ostride;
    float acc[8];
#pragma unroll
    for (int j = 0; j < 8; ++j) acc[j] = Bw[c0 + j];
    int j1 = aoff[n + 1];
    for (int jj = aoff[n]; jj < j1; ++jj) {
        int e = aeid[jj], s = aei[e];
        float nm = nrm[e];
        uint4 hv = *(const uint4*)(Hk + (size_t)s * HA + c0);
        acc[0] += nm * b2f((u16)(hv.x & 0xffff));
        acc[1] += nm * b2f((u16)(hv.x >> 16));
        acc[2] += nm * b2f((u16)(hv.y & 0xffff));
        acc[3] += nm * b2f((u16)(hv.y >> 16));
        acc[4] += nm * b2f((u16)(hv.z & 0xffff));
        acc[5] += nm * b2f((u16)(hv.z >> 16));
        acc[6] += nm * b2f((u16)(hv.w & 0xffff));
        acc[7] += nm * b2f((u16)(hv.w >> 16));
    }
    for (int f = 0; f < 28; ++f) {
        float av = Aas[nl][f];
        const float* wr = &Rw[f * 128 + c0];
        float4 w0 = *(const float4*)wr, w1 = *(const float4*)(wr + 4);
        acc[0] += av * w0.x; acc[1] += av * w0.y; acc[2] += av * w0.z; acc[3] += av * w0.w;
        acc[4] += av * w1.x; acc[5] += av * w1.y; acc[6] += av * w1.z; acc[7] += av * w1.w;
    }
#pragma unroll
    for (int j = 0; j < 8; ++j) acc[j] = fmaxf(acc[j], 0.f);
    uint4 pk;
    pk.x = (u32)f2b(acc[0]) | ((u32)f2b(acc[1]) << 16);
    pk.y = (u32)f2b(acc[2]) | ((u32)f2b(acc[3]) << 16);
    pk.z = (u32)f2b(acc[4]) | ((u32)f2b(acc[5]) << 16);
    pk.w = (u32)f2b(acc[6]) | ((u32)f2b(acc[7]) << 16);
    *(uint4*)(Ok + (size_t)n * HA + c0) = pk;
}

// ---------------------------------------------------------------------------
// head2: fused readout (sorted amino_batch segmented sum over bf16 O) + MLP.
__global__ __launch_bounds__(256) void head2(
    const u16* __restrict__ O, size_t kstride, const int* __restrict__ bat,
    const float* __restrict__ l1w, const float* __restrict__ l1b,
    const float* __restrict__ l2w, const float* __restrict__ l2b,
    const float* __restrict__ l3w, const float* __restrict__ l3b,
    const float* __restrict__ l4w, const float* __restrict__ l4b,
    float* __restrict__ outp) {
    __shared__ float sg[HA], sp1[F1], sp2[F2], sp3[F3];
    int b = blockIdx.x, tx = threadIdx.x;
    int lo = 0, hi = N_AMINO;
    while (lo < hi) { int mid = (lo + hi) >> 1; if (bat[mid] < b) lo = mid + 1; else hi = mid; }
    int s = lo;
    lo = 0; hi = N_AMINO;
    while (lo < hi) { int mid = (lo + hi) >> 1; if (bat[mid] < b + 1) lo = mid + 1; else hi = mid; }
    int e = lo;
    if (tx < HA) {
        float acc = 0.f;
        for (int n = s; n < e; ++n)
            acc += b2f(O[(size_t)n * HA + tx]) + b2f(O[kstride + (size_t)n * HA + tx])
                 + b2f(O[2 * kstride + (size_t)n * HA + tx]);
        sg[tx] = acc * (1.f / 3.f);
    }
    __syncthreads();
    {   float acc = l1b[tx];
        for (int f = 0; f < HA; ++f) acc += sg[f] * l1w[f * F1 + tx];
        sp1[tx] = fmaxf(acc, 0.f); }
    __syncthreads();
    if (tx < F2) {
        float acc = l2b[tx];
        for (int f = 0; f < F1; ++f) acc += sp1[f] * l2w[f * F2 + tx];
        sp2[tx] = fmaxf(acc, 0.f); }
    __syncthreads();
    if (tx < F3) {
        float acc = l3b[tx];
        for (int f = 0; f < F2; ++f) acc += sp2[f] * l3w[f * F3 + tx];
        sp3[tx] = fmaxf(acc, 0.f); }
    __syncthreads();
    if (tx < 64) {
        float p = sp3[tx] * l4w[tx];
        for (int off = 32; off > 0; off >>= 1) p += __shfl_down(p, off, 64);
        if (tx == 0) outp[b] = p + l4b[0];
    }
}

// ---------------------------------------------------------------------------
// Workspace (<= 34,348,288 B, proven available).
#define OFF_M1    ((size_t)0)
#define OFF_M2    ((size_t)38400)
#define OFF_M3    ((size_t)57600)
#define OFF_AOFF  ((size_t)76800)
#define OFF_AEID  ((size_t)118016)
#define OFF_NRM   ((size_t)199936)
#define OFF_AA    ((size_t)281856)
#define OFF_HA    ((size_t)2891008)
#define OFF_HB    ((size_t)6891008)
#define OFF_MSG   ((size_t)10891008)
#define OFF_SOFF  ((size_t)18891008)
#define OFF_DOFF  ((size_t)19291136)
#define OFF_DSLOT ((size_t)19691264)
#define OFF_LOFF  ((size_t)20491264)
#define OFF_LNID  ((size_t)20532480)
#define OFF_CS    ((size_t)20932480)
#define OFF_CD    ((size_t)21332480)
#define OFF_CA    ((size_t)21732480)
#define OFF_CL    ((size_t)21773440)
#define OFF_US    ((size_t)21814400)
#define OFF_UD    ((size_t)22214400)
#define OFF_UA    ((size_t)22614400)
#define OFF_UL    ((size_t)22655360)
#define OFF_BSUM  ((size_t)22696320)
#define OFF_EAP   ((size_t)22697216)      // bf16x12 4,800,000 -> 27,497,216
#define OFF_SRCP  ((size_t)27497216)      // 800,000 -> 28,297,216
#define OFF_WP    ((size_t)28297216)      // 589,824 -> 28,887,040
// ARMA overlay: H bf16 2,891,008..10,755,328; O bf16 18,619,648..26,483,968.
#define OFF_ARH   ((size_t)2891008)
#define OFF_ARO   ((size_t)18619648)

extern "C" void kernel_launch(void* const* d_in, const int* in_sizes, int n_in,
                              void* d_out, int out_size, void* d_ws, size_t ws_size,
                              hipStream_t stream) {
    (void)in_sizes; (void)n_in; (void)out_size; (void)ws_size;
    const float* x   = (const float*)d_in[0];
    const int*   ei  = (const int*)d_in[1];
    const float* ea  = (const float*)d_in[2];
    const int*   lbl = (const int*)d_in[3];
    const float* af  = (const float*)d_in[4];
    const int*   aei = (const int*)d_in[5];
    const int*   bat = (const int*)d_in[6];
    const float* nn1w = (const float*)d_in[7];  const float* nn1b = (const float*)d_in[8];
    const float* rt1  = (const float*)d_in[9];  const float* b1   = (const float*)d_in[10];
    const float* nn2w = (const float*)d_in[11]; const float* nn2b = (const float*)d_in[12];
    const float* rt2  = (const float*)d_in[13]; const float* b2   = (const float*)d_in[14];
    const float* nn3w = (const float*)d_in[15]; const float* nn3b = (const float*)d_in[16];
    const float* rt3  = (const float*)d_in[17]; const float* b3   = (const float*)d_in[18];
    const float* ai   = (const float*)d_in[19]; const float* aw   = (const float*)d_in[20];
    const float* arw  = (const float*)d_in[21]; const float* abi  = (const float*)d_in[22];
    const float* l1w  = (const float*)d_in[23]; const float* l1b  = (const float*)d_in[24];
    const float* l2w  = (const float*)d_in[25]; const float* l2b  = (const float*)d_in[26];
    const float* l3w  = (const float*)d_in[27]; const float* l3b  = (const float*)d_in[28];
    const float* l4w  = (const float*)d_in[29]; const float* l4b  = (const float*)d_in[30];
    float* outp = (float*)d_out;

    char* ws = (char*)d_ws;
    float* M1    = (float*)(ws + OFF_M1);
    float* M2    = (float*)(ws + OFF_M2);
    float* M3    = (float*)(ws + OFF_M3);
    int*   aoff  = (int*)(ws + OFF_AOFF);
    int*   aeid  = (int*)(ws + OFF_AEID);
    float* nrm   = (float*)(ws + OFF_NRM);
    float* aa    = (float*)(ws + OFF_AA);
    u16*   hA    = (u16*)(ws + OFF_HA);
    u16*   hB    = (u16*)(ws + OFF_HB);
    u16*   msg   = (u16*)(ws + OFF_MSG);
    int*   soff  = (int*)(ws + OFF_SOFF);
    int*   doff  = (int*)(ws + OFF_DOFF);
    int*   dslot = (int*)(ws + OFF_DSLOT);
    int*   loff  = (int*)(ws + OFF_LOFF);
    int*   lnid  = (int*)(ws + OFF_LNID);
    int*   cs    = (int*)(ws + OFF_CS);
    int*   cd    = (int*)(ws + OFF_CD);
    int*   ca    = (int*)(ws + OFF_CA);
    int*   cl    = (int*)(ws + OFF_CL);
    int*   us    = (int*)(ws + OFF_US);
    int*   ud    = (int*)(ws + OFF_UD);
    int*   ua    = (int*)(ws + OFF_UA);
    int*   ul    = (int*)(ws + OFF_UL);
    int*   bsum  = (int*)(ws + OFF_BSUM);
    u16*   eaP   = (u16*)(ws + OFF_EAP);
    int*   srcP  = (int*)(ws + OFF_SRCP);
    u16*   Wp    = (u16*)(ws + OFF_WP);
    u16*   Hb    = (u16*)(ws + OFF_ARH);
    u16*   Obh   = (u16*)(ws + OFF_ARO);

    const int* esrc = ei;
    const int* edst = ei + E_ATOMS;
    const int* adst = aei + E_AMINO;

    // prep
    k_prep0<<<(PREP0_N + 255) / 256, 256, 0, stream>>>(
        nn1w, nn1b, nn2w, nn2b, nn3w, nn3b, M1, M2, M3, af, aa, cs, cd, ca, cl);
    k_cvtwp<<<((TL - 1) * KS * 16384 + 255) / 256, 256, 0, stream>>>(aw, Wp);
    k_csr_count<<<(2 * E_ATOMS + E_AMINO + N_ATOMS + 255) / 256, 256, 0, stream>>>(
        esrc, edst, adst, lbl, cs, cd, ca, cl);
    k_scan1<<<2 * NBS + 2 * NBA, 256, 0, stream>>>(cs, soff, cd, doff, ca, aoff, cl, loff, bsum);
    k_scan2<<<4, 128, 0, stream>>>(bsum, soff, doff, aoff, loff);
    k_scan3<<<2 * NBS + 2 * NBA, 256, 0, stream>>>(soff, doff, aoff, loff, bsum, us, ud, ua, ul);
    k_csr_fill<<<(E_ATOMS + 2 * E_AMINO + N_ATOMS + 255) / 256, 256, 0, stream>>>(
        esrc, edst, ea, us, srcP, eaP, ud, dslot, aei, ua, aeid, aoff, nrm, lbl, ul, lnid);

    // NNConv (x tile staged in LDS, vectorized eaP)
    const int GT = N_ATOMS / TILE;                // 3125
    const int GF = (N_ATOMS * HD + 255) / 256;    // 7813
    nnconv_edge6<DIN0, true ><<<GT, 256, 0, stream>>>(x,  eaP, srcP, soff, M1, msg);
    nnconv_reduce<DIN0, true ><<<GF, 256, 0, stream>>>(x,  rt1, b1, doff, dslot, msg, hA);
    nnconv_edge6<HD,   false><<<GT, 256, 0, stream>>>(hA, eaP, srcP, soff, M2, msg);
    nnconv_reduce<HD,   false><<<GF, 256, 0, stream>>>(hA, rt2, b2, doff, dslot, msg, hB);
    nnconv_edge6<HD,   false><<<GT, 256, 0, stream>>>(hB, eaP, srcP, soff, M3, msg);
    nnconv_reduce<HD,   false><<<GF, 256, 0, stream>>>(hB, rt3, b3, doff, dslot, msg, hA);
    aa_gather<<<(N_AMINO * HD + 255) / 256, 256, 0, stream>>>(hA, loff, lnid, aa);

    // ARMA: K-parallel, T layers; bf16 H/O, MFMA gemms
    const size_t KH = (size_t)N_AMINO * HA;
    for (int t = 0; t < TL; ++t) {
        if (t == 0)
            arma_gemm28<<<dim3(640, KS), 256, 0, stream>>>(aa, ai, 28 * HA, Hb, KH);
        else
            arma_gemm_mf<<<dim3(160, KS), 256, 0, stream>>>(
                Obh, KH, Wp + (size_t)(t - 1) * KS * 16384, Hb, KH);
        arma_out<<<dim3(640, KS), 256, 0, stream>>>(
            Hb, KH, aa, arw + (size_t)t * KS * 28 * HA, 28 * HA,
            abi + (size_t)t * KS * HA, HA, aei, aoff, aeid, nrm, Obh, KH);
    }

    head2<<<NGRAPH, 256, 0, stream>>>(Obh, KH, bat, l1w, l1b, l2w, l2b,
                                      l3w, l3b, l4w, l4b, outp);
}